// Round 1
// baseline (3201.784 us; speedup 1.0000x reference)
//
#include <hip/hip_runtime.h>
#include <math.h>

#define NNODES 51200
#define BGRAPHS 128
#define NPG 400
#define NEDGES 819200

// ---------------------------------------------------------------- utilities
__global__ void init_nmask_kernel(float* __restrict__ nmask) {
    int i = blockIdx.x * blockDim.x + threadIdx.x;
    if (i < NNODES) nmask[i] = 1.0f;
}

// deg[d] += 1 for each active edge (emask = nmask[src]*nmask[dst])
__global__ void deg_scatter_kernel(const int* __restrict__ src, const int* __restrict__ dst,
                                   const float* __restrict__ nmask, float* __restrict__ deg) {
    int e = blockIdx.x * blockDim.x + threadIdx.x;
    if (e < NEDGES) {
        int s = src[e], d = dst[e];
        if (nmask[s] > 0.0f && nmask[d] > 0.0f) atomicAdd(deg + d, 1.0f);
    }
}

// deg -> dinv in place (deg += nmask for the self term first)
__global__ void dinv_kernel(float* __restrict__ deg, const float* __restrict__ nmask) {
    int i = blockIdx.x * blockDim.x + threadIdx.x;
    if (i < NNODES) {
        float d = deg[i] + nmask[i];
        deg[i] = (d > 0.0f) ? rsqrtf(d) : 0.0f;
    }
}

// per-edge norm = dinv[src]*dinv[dst]  (zero if either endpoint masked)
__global__ void enorm_kernel(const int* __restrict__ src, const int* __restrict__ dst,
                             const float* __restrict__ dinv, float* __restrict__ enorm) {
    int e = blockIdx.x * blockDim.x + threadIdx.x;
    if (e < NEDGES) enorm[e] = dinv[src[e]] * dinv[dst[e]];
}

// --------------------------------------------------------------------- GEMM
// H = X @ W ; AGG = H * dinv^2 (self-loop init). 64 rows per 256-thread block.
template<int IN, int OUT>
__global__ __launch_bounds__(256) void gemm_selfinit_kernel(
    const float* __restrict__ X, const float* __restrict__ W,
    const float* __restrict__ dinv, float* __restrict__ H, float* __restrict__ AGG) {
    __shared__ float sX[64 * IN];
    const int row0 = blockIdx.x * 64;
    const int t = threadIdx.x;
    for (int i = t; i < 64 * IN; i += 256) sX[i] = X[(size_t)row0 * IN + i];
    __syncthreads();
    constexpr int GROUPS = 256 / OUT;   // 8,4,2
    constexpr int RPT    = 64 / GROUPS; // 8,16,32
    const int c  = t % OUT;
    const int r0 = (t / OUT) * RPT;
    float acc[RPT];
#pragma unroll
    for (int rr = 0; rr < RPT; rr++) acc[rr] = 0.0f;
    for (int j4 = 0; j4 < IN / 4; j4++) {
        const float w0 = W[(j4 * 4 + 0) * OUT + c];
        const float w1 = W[(j4 * 4 + 1) * OUT + c];
        const float w2 = W[(j4 * 4 + 2) * OUT + c];
        const float w3 = W[(j4 * 4 + 3) * OUT + c];
#pragma unroll
        for (int rr = 0; rr < RPT; rr++) {
            const float4 xv = *reinterpret_cast<const float4*>(&sX[(r0 + rr) * IN + j4 * 4]);
            acc[rr] += xv.x * w0 + xv.y * w1 + xv.z * w2 + xv.w * w3;
        }
    }
#pragma unroll
    for (int rr = 0; rr < RPT; rr++) {
        const int r = row0 + r0 + rr;
        const float dv = dinv[r];
        const float v = acc[rr];
        H[(size_t)r * OUT + c]   = v;
        AGG[(size_t)r * OUT + c] = v * dv * dv;
    }
}

// ------------------------------------------------------------------ scatter
// AGG[dst] += H[src] * enorm, thread = (edge, 4-feature chunk)
template<int OUT>
__global__ void scatter_kernel(const float* __restrict__ H, float* __restrict__ AGG,
                               const int* __restrict__ src, const int* __restrict__ dst,
                               const float* __restrict__ enorm) {
    constexpr int F4 = OUT / 4;
    int i = blockIdx.x * blockDim.x + threadIdx.x;
    int e = i / F4;
    int f = i % F4;
    if (e >= NEDGES) return;
    float nrm = enorm[e];
    if (nrm == 0.0f) return;
    int s = src[e], d = dst[e];
    const float4 h4 = *reinterpret_cast<const float4*>(&H[(size_t)s * OUT + f * 4]);
    float* a = &AGG[(size_t)d * OUT + f * 4];
    atomicAdd(a + 0, h4.x * nrm);
    atomicAdd(a + 1, h4.y * nrm);
    atomicAdd(a + 2, h4.z * nrm);
    atomicAdd(a + 3, h4.w * nrm);
}

// --------------------------------------------------------------- finalize
// AGG = relu((AGG + b) * nmask)
template<int OUT>
__global__ void finalize_kernel(float* __restrict__ AGG, const float* __restrict__ bias,
                                const float* __restrict__ nmask) {
    constexpr int F4 = OUT / 4;
    int idx = blockIdx.x * blockDim.x + threadIdx.x; // over NNODES*F4
    int n = idx / F4;
    int f = idx % F4;
    if (n >= NNODES) return;
    float m = nmask[n];
    float4 v = reinterpret_cast<float4*>(AGG)[idx];
    const float4 b4 = reinterpret_cast<const float4*>(bias)[f];
    v.x = fmaxf((v.x + b4.x) * m, 0.0f);
    v.y = fmaxf((v.y + b4.y) * m, 0.0f);
    v.z = fmaxf((v.z + b4.z) * m, 0.0f);
    v.w = fmaxf((v.w + b4.w) * m, 0.0f);
    reinterpret_cast<float4*>(AGG)[idx] = v;
}

// ------------------------------------------------------------------- top-k
// One block per graph. Exact lax.top_k semantics via bitonic sort with
// (value desc, index asc) total order on 512 padded elements.
template<int DIM>
__global__ __launch_bounds__(512) void topk_kernel(float* __restrict__ X,
                                                   float* __restrict__ nmask,
                                                   const float* __restrict__ p, int K) {
    __shared__ float sval[512];
    __shared__ int   sidx[512];
    __shared__ float sscore[NPG];
    __shared__ float spnorm;
    const int g = blockIdx.x;
    const int t = threadIdx.x;
    if (t == 0) {
        float s = 0.0f;
        for (int j = 0; j < DIM; j++) s += p[j] * p[j];
        spnorm = sqrtf(s);
    }
    __syncthreads();
    if (t < NPG) {
        const float* xr = X + (size_t)(g * NPG + t) * DIM;
        float s = 0.0f;
        for (int j4 = 0; j4 < DIM / 4; j4++) {
            float4 xv = *reinterpret_cast<const float4*>(&xr[j4 * 4]);
            float4 pv = *reinterpret_cast<const float4*>(&p[j4 * 4]);
            s += xv.x * pv.x + xv.y * pv.y + xv.z * pv.z + xv.w * pv.w;
        }
        s /= spnorm;
        sscore[t] = s;
        sval[t] = (nmask[g * NPG + t] > 0.0f) ? s : -INFINITY;
        sidx[t] = t;
    } else {
        sval[t] = -INFINITY;
        sidx[t] = 0x7FFFFFFF;
    }
    __syncthreads();
    for (int kk = 2; kk <= 512; kk <<= 1) {
        for (int j = kk >> 1; j > 0; j >>= 1) {
            int l = t ^ j;
            if (l > t) {
                float va = sval[t], vb = sval[l];
                int   ia = sidx[t], ib = sidx[l];
                bool aFirst = (va > vb) || (va == vb && ia < ib);
                bool desc   = ((t & kk) == 0);
                if (desc != aFirst) {
                    sval[t] = vb; sval[l] = va;
                    sidx[t] = ib; sidx[l] = ia;
                }
            }
            __syncthreads();
        }
    }
    // rebuild mask
    if (t < NPG) nmask[g * NPG + t] = 0.0f;
    __syncthreads();
    if (t < K) nmask[g * NPG + sidx[t]] = 1.0f;
    __syncthreads();
    // x *= tanh(score) * new_mask
    for (int i = t; i < NPG * DIM; i += 512) {
        int n = i / DIM;
        float m = nmask[g * NPG + n];
        float f = (m > 0.0f) ? tanhf(sscore[n]) : 0.0f;
        X[(size_t)g * NPG * DIM + i] *= f;
    }
}

// --------------------------------------------------------------- max pool
__global__ void maxpool_kernel(const float* __restrict__ X, float* __restrict__ HP) {
    const int g = blockIdx.x;
    const int f = threadIdx.x; // 128
    const float* base = X + (size_t)g * NPG * 128 + f;
    float m = 0.0f; // post-relu values are >= 0
    for (int n = 0; n < NPG; n++) m = fmaxf(m, base[n * 128]);
    HP[g * 128 + f] = m;
}

// -------------------------------------------------------------------- head
__device__ __forceinline__ void lin_bn_layer(float* A, float* Bf, float* smv,
                                             int in, int out,
                                             const float* __restrict__ W,
                                             const float* __restrict__ b,
                                             const float* __restrict__ ga,
                                             const float* __restrict__ be, int t) {
    const int tot = 128 * out;
    for (int i = t; i < tot; i += 256) {
        int r = i / out, c = i - r * out;
        float acc = b[c];
        for (int j = 0; j < in; j++) acc += A[r * in + j] * W[j * out + c];
        Bf[i] = acc;
    }
    __syncthreads();
    if (t < out) {
        float m = 0.0f;
        for (int r = 0; r < 128; r++) m += Bf[r * out + t];
        m *= (1.0f / 128.0f);
        float v = 0.0f;
        for (int r = 0; r < 128; r++) { float d2 = Bf[r * out + t] - m; v += d2 * d2; }
        v *= (1.0f / 128.0f);
        smv[t] = m; smv[64 + t] = v;
    }
    __syncthreads();
    for (int i = t; i < tot; i += 256) {
        int c = i % out;
        float val = ga[c] * (Bf[i] - smv[c]) * rsqrtf(smv[64 + c] + 1e-5f) + be[c];
        A[i] = val > 0.0f ? val : 0.0f;
    }
    __syncthreads();
}

__global__ __launch_bounds__(256) void head_kernel(
    const float* __restrict__ HP,
    const float* __restrict__ Lw1, const float* __restrict__ Lb1,
    const float* __restrict__ Lw2, const float* __restrict__ Lb2,
    const float* __restrict__ Lw3, const float* __restrict__ Lb3,
    const float* __restrict__ Lw4, const float* __restrict__ Lb4,
    const float* __restrict__ Lw5, const float* __restrict__ Lb5,
    const float* __restrict__ g1, const float* __restrict__ be1,
    const float* __restrict__ g2, const float* __restrict__ be2,
    const float* __restrict__ g3, const float* __restrict__ be3,
    const float* __restrict__ g4, const float* __restrict__ be4,
    float* __restrict__ out) {
    __shared__ float A[128 * 128];
    __shared__ float Bf[128 * 64];
    __shared__ float smv[128];
    const int t = threadIdx.x;
    for (int i = t; i < 128 * 128; i += 256) A[i] = HP[i];
    __syncthreads();
    lin_bn_layer(A, Bf, smv, 128, 64, Lw1, Lb1, g1, be1, t);
    lin_bn_layer(A, Bf, smv, 64, 64, Lw2, Lb2, g2, be2, t);
    lin_bn_layer(A, Bf, smv, 64, 32, Lw3, Lb3, g3, be3, t);
    lin_bn_layer(A, Bf, smv, 32, 16, Lw4, Lb4, g4, be4, t);
    if (t < 128) {
        float acc = Lb5[0];
        for (int j = 0; j < 16; j++) acc += A[t * 16 + j] * Lw5[j];
        out[t] = acc;
    }
}

// ------------------------------------------------------------------ driver
template<int IN, int OUT>
static void run_conv(const float* Xin, const float* W, const float* b,
                     float* H, float* AGG, float* dinv, float* nmask, float* enorm,
                     const int* src, const int* dst, hipStream_t stream) {
    hipMemsetAsync(dinv, 0, NNODES * sizeof(float), stream);
    deg_scatter_kernel<<<NEDGES / 256, 256, 0, stream>>>(src, dst, nmask, dinv);
    dinv_kernel<<<NNODES / 256, 256, 0, stream>>>(dinv, nmask);
    enorm_kernel<<<NEDGES / 256, 256, 0, stream>>>(src, dst, dinv, enorm);
    gemm_selfinit_kernel<IN, OUT><<<NNODES / 64, 256, 0, stream>>>(Xin, W, dinv, H, AGG);
    scatter_kernel<OUT><<<(NEDGES * (OUT / 4)) / 256, 256, 0, stream>>>(H, AGG, src, dst, enorm);
    finalize_kernel<OUT><<<(NNODES * (OUT / 4)) / 256, 256, 0, stream>>>(AGG, b, nmask);
}

extern "C" void kernel_launch(void* const* d_in, const int* in_sizes, int n_in,
                              void* d_out, int out_size, void* d_ws, size_t ws_size,
                              hipStream_t stream) {
    (void)in_sizes; (void)n_in; (void)out_size; (void)ws_size;
    const float* x   = (const float*)d_in[0];
    const int*   ei  = (const int*)d_in[1];
    const float* W1  = (const float*)d_in[3];  const float* b1  = (const float*)d_in[4];
    const float* W2  = (const float*)d_in[5];  const float* b2  = (const float*)d_in[6];
    const float* W3  = (const float*)d_in[7];  const float* b3  = (const float*)d_in[8];
    const float* W4  = (const float*)d_in[9];  const float* b4  = (const float*)d_in[10];
    const float* p1  = (const float*)d_in[11];
    const float* p2  = (const float*)d_in[12];
    const float* p3  = (const float*)d_in[13];
    const float* Lw1 = (const float*)d_in[14]; const float* Lb1 = (const float*)d_in[15];
    const float* Lw2 = (const float*)d_in[16]; const float* Lb2 = (const float*)d_in[17];
    const float* Lw3 = (const float*)d_in[18]; const float* Lb3 = (const float*)d_in[19];
    const float* Lw4 = (const float*)d_in[20]; const float* Lb4 = (const float*)d_in[21];
    const float* Lw5 = (const float*)d_in[22]; const float* Lb5 = (const float*)d_in[23];
    const float* g1  = (const float*)d_in[24]; const float* be1 = (const float*)d_in[25];
    const float* g2  = (const float*)d_in[26]; const float* be2 = (const float*)d_in[27];
    const float* g3  = (const float*)d_in[28]; const float* be3 = (const float*)d_in[29];
    const float* g4  = (const float*)d_in[30]; const float* be4 = (const float*)d_in[31];

    const int* src = ei;
    const int* dst = ei + NEDGES;

    float* ws    = (float*)d_ws;
    float* hb    = ws;                           // NNODES*128
    float* x0    = hb + (size_t)NNODES * 128;    // NNODES*128
    float* x1    = x0 + (size_t)NNODES * 128;    // NNODES*128
    float* dinv  = x1 + (size_t)NNODES * 128;    // NNODES
    float* nmask = dinv + NNODES;                // NNODES
    float* enorm = nmask + NNODES;               // NEDGES
    float* hp    = enorm + NEDGES;               // BGRAPHS*128

    init_nmask_kernel<<<NNODES / 256, 256, 0, stream>>>(nmask);

    // conv1: 64 -> 32
    run_conv<64, 32>(x, W1, b1, hb, x0, dinv, nmask, enorm, src, dst, stream);
    topk_kernel<32><<<BGRAPHS, 512, 0, stream>>>(x0, nmask, p1, 360);
    // conv2: 32 -> 64
    run_conv<32, 64>(x0, W2, b2, hb, x1, dinv, nmask, enorm, src, dst, stream);
    topk_kernel<64><<<BGRAPHS, 512, 0, stream>>>(x1, nmask, p2, 324);
    // conv3: 64 -> 128
    run_conv<64, 128>(x1, W3, b3, hb, x0, dinv, nmask, enorm, src, dst, stream);
    topk_kernel<128><<<BGRAPHS, 512, 0, stream>>>(x0, nmask, p3, 292);
    // conv4: 128 -> 128
    run_conv<128, 128>(x0, W4, b4, hb, x1, dinv, nmask, enorm, src, dst, stream);

    maxpool_kernel<<<BGRAPHS, 128, 0, stream>>>(x1, hp);
    head_kernel<<<1, 256, 0, stream>>>(hp,
        Lw1, Lb1, Lw2, Lb2, Lw3, Lb3, Lw4, Lb4, Lw5, Lb5,
        g1, be1, g2, be2, g3, be3, g4, be4, (float*)d_out);
}

// Round 2
// 685.194 us; speedup vs baseline: 4.6728x; 4.6728x over previous
//
#include <hip/hip_runtime.h>
#include <math.h>

#define NNODES 51200
#define BGRAPHS 128
#define NPG 400
#define NEDGES 819200
#define EPG 6400   // edges per graph

// ---------------------------------------------------------------- utilities
__global__ void init_nmask_kernel(float* __restrict__ nmask) {
    int i = blockIdx.x * blockDim.x + threadIdx.x;
    if (i < NNODES) nmask[i] = 1.0f;
}

// ---------------------------------------------------------------- CSR build
// One block per graph: bucket edges by local dst. Mask-independent, built once.
__global__ __launch_bounds__(512) void csr_build_kernel(
    const int* __restrict__ src, const int* __restrict__ dst,
    unsigned short* __restrict__ srcl, int* __restrict__ rowptr) {
    __shared__ int hist[NPG];
    __shared__ int offs[NPG + 1];
    const int g = blockIdx.x;
    const int t = threadIdx.x;
    for (int i = t; i < NPG; i += 512) hist[i] = 0;
    __syncthreads();
    for (int e = t; e < EPG; e += 512)
        atomicAdd(&hist[dst[g * EPG + e] - g * NPG], 1);
    __syncthreads();
    if (t == 0) {
        int s = 0;
        for (int i = 0; i < NPG; i++) { offs[i] = s; s += hist[i]; }
        offs[NPG] = s;
    }
    __syncthreads();
    for (int i = t; i <= NPG; i += 512) rowptr[g * (NPG + 1) + i] = offs[i];
    for (int i = t; i < NPG; i += 512) hist[i] = offs[i];  // cursors
    __syncthreads();
    for (int e = t; e < EPG; e += 512) {
        int dl = dst[g * EPG + e] - g * NPG;
        int pos = atomicAdd(&hist[dl], 1);
        srcl[g * EPG + pos] = (unsigned short)(src[g * EPG + e] - g * NPG);
    }
}

// --------------------------------------------------------------------- GEMM
// H = X @ W. 64 rows per 256-thread block.
template<int IN, int OUT>
__global__ __launch_bounds__(256) void gemm_kernel(
    const float* __restrict__ X, const float* __restrict__ W,
    float* __restrict__ H) {
    __shared__ float sX[64 * IN];
    const int row0 = blockIdx.x * 64;
    const int t = threadIdx.x;
    for (int i = t; i < 64 * IN; i += 256) sX[i] = X[(size_t)row0 * IN + i];
    __syncthreads();
    constexpr int GROUPS = 256 / OUT;   // 8,4,2
    constexpr int RPT    = 64 / GROUPS; // 8,16,32
    const int c  = t % OUT;
    const int r0 = (t / OUT) * RPT;
    float acc[RPT];
#pragma unroll
    for (int rr = 0; rr < RPT; rr++) acc[rr] = 0.0f;
    for (int j4 = 0; j4 < IN / 4; j4++) {
        const float w0 = W[(j4 * 4 + 0) * OUT + c];
        const float w1 = W[(j4 * 4 + 1) * OUT + c];
        const float w2 = W[(j4 * 4 + 2) * OUT + c];
        const float w3 = W[(j4 * 4 + 3) * OUT + c];
#pragma unroll
        for (int rr = 0; rr < RPT; rr++) {
            const float4 xv = *reinterpret_cast<const float4*>(&sX[(r0 + rr) * IN + j4 * 4]);
            acc[rr] += xv.x * w0 + xv.y * w1 + xv.z * w2 + xv.w * w3;
        }
    }
#pragma unroll
    for (int rr = 0; rr < RPT; rr++)
        H[(size_t)(row0 + r0 + rr) * OUT + c] = acc[rr];
}

// ---------------------------------------------------------------- aggregate
// One block per (graph, CH-feature chunk). All-LDS CSR gather:
//   Y = relu((D^-1/2 (A+I) D^-1/2 H + b)) * nmask   for this chunk's columns.
// dinv computed in-block from staged nmask (no global deg/dinv kernels).
template<int OUT, int CH>
__global__ __launch_bounds__(512) void gcn_agg_kernel(
    const float* __restrict__ H, float* __restrict__ Y,
    const float* __restrict__ nmask, const float* __restrict__ bias,
    const unsigned short* __restrict__ srcl, const int* __restrict__ rowptr) {
    constexpr int NCH = OUT / CH;
    __shared__ float Hl[NPG * CH];
    __shared__ float dinvl[NPG];
    __shared__ float nml[NPG];
    __shared__ unsigned short sl[EPG];
    __shared__ int rp[NPG + 1];
    const int g  = blockIdx.x / NCH;
    const int f0 = (blockIdx.x % NCH) * CH;
    const int t  = threadIdx.x;

    for (int i = t; i < NPG; i += 512) nml[i] = nmask[g * NPG + i];
    for (int i = t; i <= NPG; i += 512) rp[i] = rowptr[g * (NPG + 1) + i];
    for (int i = t; i < EPG / 2; i += 512)
        reinterpret_cast<unsigned int*>(sl)[i] =
            reinterpret_cast<const unsigned int*>(srcl + g * EPG)[i];
    for (int i = t; i < NPG * (CH / 4); i += 512) {
        int n = i / (CH / 4), fq = i % (CH / 4);
        reinterpret_cast<float4*>(Hl)[i] =
            *reinterpret_cast<const float4*>(&H[(size_t)(g * NPG + n) * OUT + f0 + fq * 4]);
    }
    __syncthreads();

    // per-node dinv from CSR (deg counts active->active edges only)
    for (int n = t; n < NPG; n += 512) {
        float d = 0.0f;
        if (nml[n] > 0.0f) {
            d = nml[n];
            for (int e = rp[n]; e < rp[n + 1]; e++) d += nml[sl[e]];
        }
        dinvl[n] = (d > 0.0f) ? rsqrtf(d) : 0.0f;
    }
    __syncthreads();

    // gather: wave-group (CH lanes) per dst node
    constexpr int GPW = 64 / CH;          // node groups per wave
    const int wave = t >> 6, lane = t & 63;
    const int grp  = lane / CH;
    const int f    = lane % CH;
    const float bv = bias[f0 + f];
    for (int n = wave * GPW + grp; n < NPG; n += 8 * GPW) {
        const float di = dinvl[n];
        float acc = Hl[n * CH + f] * di * di;   // self-loop
        const int e1 = rp[n + 1];
        for (int e = rp[n]; e < e1; e++) {
            const int s = sl[e];
            acc += Hl[s * CH + f] * (dinvl[s] * di);
        }
        float v = fmaxf(acc + bv, 0.0f);
        Y[(size_t)(g * NPG + n) * OUT + f0 + f] = (nml[n] > 0.0f) ? v : 0.0f;
    }
}

// ------------------------------------------------------------------- top-k
// One block per graph. Exact lax.top_k semantics via bitonic sort with
// (value desc, index asc) total order on 512 padded elements.
template<int DIM>
__global__ __launch_bounds__(512) void topk_kernel(float* __restrict__ X,
                                                   float* __restrict__ nmask,
                                                   const float* __restrict__ p, int K) {
    __shared__ float sval[512];
    __shared__ int   sidx[512];
    __shared__ float sscore[NPG];
    __shared__ float spnorm;
    const int g = blockIdx.x;
    const int t = threadIdx.x;
    if (t == 0) {
        float s = 0.0f;
        for (int j = 0; j < DIM; j++) s += p[j] * p[j];
        spnorm = sqrtf(s);
    }
    __syncthreads();
    if (t < NPG) {
        const float* xr = X + (size_t)(g * NPG + t) * DIM;
        float s = 0.0f;
        for (int j4 = 0; j4 < DIM / 4; j4++) {
            float4 xv = *reinterpret_cast<const float4*>(&xr[j4 * 4]);
            float4 pv = *reinterpret_cast<const float4*>(&p[j4 * 4]);
            s += xv.x * pv.x + xv.y * pv.y + xv.z * pv.z + xv.w * pv.w;
        }
        s /= spnorm;
        sscore[t] = s;
        sval[t] = (nmask[g * NPG + t] > 0.0f) ? s : -INFINITY;
        sidx[t] = t;
    } else {
        sval[t] = -INFINITY;
        sidx[t] = 0x7FFFFFFF;
    }
    __syncthreads();
    for (int kk = 2; kk <= 512; kk <<= 1) {
        for (int j = kk >> 1; j > 0; j >>= 1) {
            int l = t ^ j;
            if (l > t) {
                float va = sval[t], vb = sval[l];
                int   ia = sidx[t], ib = sidx[l];
                bool aFirst = (va > vb) || (va == vb && ia < ib);
                bool desc   = ((t & kk) == 0);
                if (desc != aFirst) {
                    sval[t] = vb; sval[l] = va;
                    sidx[t] = ib; sidx[l] = ia;
                }
            }
            __syncthreads();
        }
    }
    if (t < NPG) nmask[g * NPG + t] = 0.0f;
    __syncthreads();
    if (t < K) nmask[g * NPG + sidx[t]] = 1.0f;
    __syncthreads();
    for (int i = t; i < NPG * DIM; i += 512) {
        int n = i / DIM;
        float m = nmask[g * NPG + n];
        float fct = (m > 0.0f) ? tanhf(sscore[n]) : 0.0f;
        X[(size_t)g * NPG * DIM + i] *= fct;
    }
}

// --------------------------------------------------------------- max pool
__global__ void maxpool_kernel(const float* __restrict__ X, float* __restrict__ HP) {
    const int g = blockIdx.x;
    const int f = threadIdx.x; // 128
    const float* base = X + (size_t)g * NPG * 128 + f;
    float m = 0.0f; // post-relu values are >= 0
    for (int n = 0; n < NPG; n++) m = fmaxf(m, base[n * 128]);
    HP[g * 128 + f] = m;
}

// -------------------------------------------------------------------- head
__device__ __forceinline__ void lin_bn_layer(float* A, float* Bf, float* smv,
                                             int in, int out,
                                             const float* __restrict__ W,
                                             const float* __restrict__ b,
                                             const float* __restrict__ ga,
                                             const float* __restrict__ be, int t) {
    const int tot = 128 * out;
    for (int i = t; i < tot; i += 256) {
        int r = i / out, c = i - r * out;
        float acc = b[c];
        for (int j = 0; j < in; j++) acc += A[r * in + j] * W[j * out + c];
        Bf[i] = acc;
    }
    __syncthreads();
    if (t < out) {
        float m = 0.0f;
        for (int r = 0; r < 128; r++) m += Bf[r * out + t];
        m *= (1.0f / 128.0f);
        float v = 0.0f;
        for (int r = 0; r < 128; r++) { float d2 = Bf[r * out + t] - m; v += d2 * d2; }
        v *= (1.0f / 128.0f);
        smv[t] = m; smv[64 + t] = v;
    }
    __syncthreads();
    for (int i = t; i < tot; i += 256) {
        int c = i % out;
        float val = ga[c] * (Bf[i] - smv[c]) * rsqrtf(smv[64 + c] + 1e-5f) + be[c];
        A[i] = val > 0.0f ? val : 0.0f;
    }
    __syncthreads();
}

__global__ __launch_bounds__(256) void head_kernel(
    const float* __restrict__ HP,
    const float* __restrict__ Lw1, const float* __restrict__ Lb1,
    const float* __restrict__ Lw2, const float* __restrict__ Lb2,
    const float* __restrict__ Lw3, const float* __restrict__ Lb3,
    const float* __restrict__ Lw4, const float* __restrict__ Lb4,
    const float* __restrict__ Lw5, const float* __restrict__ Lb5,
    const float* __restrict__ g1, const float* __restrict__ be1,
    const float* __restrict__ g2, const float* __restrict__ be2,
    const float* __restrict__ g3, const float* __restrict__ be3,
    const float* __restrict__ g4, const float* __restrict__ be4,
    float* __restrict__ out) {
    __shared__ float A[128 * 128];
    __shared__ float Bf[128 * 64];
    __shared__ float smv[128];
    const int t = threadIdx.x;
    for (int i = t; i < 128 * 128; i += 256) A[i] = HP[i];
    __syncthreads();
    lin_bn_layer(A, Bf, smv, 128, 64, Lw1, Lb1, g1, be1, t);
    lin_bn_layer(A, Bf, smv, 64, 64, Lw2, Lb2, g2, be2, t);
    lin_bn_layer(A, Bf, smv, 64, 32, Lw3, Lb3, g3, be3, t);
    lin_bn_layer(A, Bf, smv, 32, 16, Lw4, Lb4, g4, be4, t);
    if (t < 128) {
        float acc = Lb5[0];
        for (int j = 0; j < 16; j++) acc += A[t * 16 + j] * Lw5[j];
        out[t] = acc;
    }
}

// ------------------------------------------------------------------ driver
extern "C" void kernel_launch(void* const* d_in, const int* in_sizes, int n_in,
                              void* d_out, int out_size, void* d_ws, size_t ws_size,
                              hipStream_t stream) {
    (void)in_sizes; (void)n_in; (void)out_size; (void)ws_size;
    const float* x   = (const float*)d_in[0];
    const int*   ei  = (const int*)d_in[1];
    const float* W1  = (const float*)d_in[3];  const float* b1  = (const float*)d_in[4];
    const float* W2  = (const float*)d_in[5];  const float* b2  = (const float*)d_in[6];
    const float* W3  = (const float*)d_in[7];  const float* b3  = (const float*)d_in[8];
    const float* W4  = (const float*)d_in[9];  const float* b4  = (const float*)d_in[10];
    const float* p1  = (const float*)d_in[11];
    const float* p2  = (const float*)d_in[12];
    const float* p3  = (const float*)d_in[13];
    const float* Lw1 = (const float*)d_in[14]; const float* Lb1 = (const float*)d_in[15];
    const float* Lw2 = (const float*)d_in[16]; const float* Lb2 = (const float*)d_in[17];
    const float* Lw3 = (const float*)d_in[18]; const float* Lb3 = (const float*)d_in[19];
    const float* Lw4 = (const float*)d_in[20]; const float* Lb4 = (const float*)d_in[21];
    const float* Lw5 = (const float*)d_in[22]; const float* Lb5 = (const float*)d_in[23];
    const float* g1  = (const float*)d_in[24]; const float* be1 = (const float*)d_in[25];
    const float* g2  = (const float*)d_in[26]; const float* be2 = (const float*)d_in[27];
    const float* g3  = (const float*)d_in[28]; const float* be3 = (const float*)d_in[29];
    const float* g4  = (const float*)d_in[30]; const float* be4 = (const float*)d_in[31];

    const int* src = ei;
    const int* dst = ei + NEDGES;

    float* ws    = (float*)d_ws;
    float* hb    = ws;                           // NNODES*128
    float* x0    = hb + (size_t)NNODES * 128;    // NNODES*128
    float* x1    = x0 + (size_t)NNODES * 128;    // NNODES*128
    float* nmask = x1 + (size_t)NNODES * 128;    // NNODES
    float* hp    = nmask + NNODES;               // BGRAPHS*128
    unsigned short* srcl = (unsigned short*)(hp + BGRAPHS * 128); // NEDGES u16
    int* rowptr  = (int*)(srcl + NEDGES);        // BGRAPHS*(NPG+1)

    init_nmask_kernel<<<NNODES / 256, 256, 0, stream>>>(nmask);
    csr_build_kernel<<<BGRAPHS, 512, 0, stream>>>(src, dst, srcl, rowptr);

    // conv1: 64 -> 32
    gemm_kernel<64, 32><<<NNODES / 64, 256, 0, stream>>>(x, W1, hb);
    gcn_agg_kernel<32, 32><<<BGRAPHS, 512, 0, stream>>>(hb, x0, nmask, b1, srcl, rowptr);
    topk_kernel<32><<<BGRAPHS, 512, 0, stream>>>(x0, nmask, p1, 360);
    // conv2: 32 -> 64
    gemm_kernel<32, 64><<<NNODES / 64, 256, 0, stream>>>(x0, W2, hb);
    gcn_agg_kernel<64, 32><<<BGRAPHS * 2, 512, 0, stream>>>(hb, x1, nmask, b2, srcl, rowptr);
    topk_kernel<64><<<BGRAPHS, 512, 0, stream>>>(x1, nmask, p2, 324);
    // conv3: 64 -> 128
    gemm_kernel<64, 128><<<NNODES / 64, 256, 0, stream>>>(x1, W3, hb);
    gcn_agg_kernel<128, 64><<<BGRAPHS * 2, 512, 0, stream>>>(hb, x0, nmask, b3, srcl, rowptr);
    topk_kernel<128><<<BGRAPHS, 512, 0, stream>>>(x0, nmask, p3, 292);
    // conv4: 128 -> 128
    gemm_kernel<128, 128><<<NNODES / 64, 256, 0, stream>>>(x0, W4, hb);
    gcn_agg_kernel<128, 64><<<BGRAPHS * 2, 512, 0, stream>>>(hb, x1, nmask, b4, srcl, rowptr);

    maxpool_kernel<<<BGRAPHS, 128, 0, stream>>>(x1, hp);
    head_kernel<<<1, 256, 0, stream>>>(hp,
        Lw1, Lb1, Lw2, Lb2, Lw3, Lb3, Lw4, Lb4, Lw5, Lb5,
        g1, be1, g2, be2, g3, be3, g4, be4, (float*)d_out);
}

// Round 3
// 471.558 us; speedup vs baseline: 6.7898x; 1.4530x over previous
//
#include <hip/hip_runtime.h>
#include <math.h>

#define NNODES 51200
#define BGRAPHS 128
#define NPG 400
#define NEDGES 819200
#define EPG 6400   // edges per graph

// ---------------- CSR build (+ nmask=1, + dinv for layer 1) ----------------
// One block per graph. Parallel Hillis-Steele scan for rowptr.
__global__ __launch_bounds__(512) void csr_build_kernel(
    const int* __restrict__ src, const int* __restrict__ dst,
    unsigned short* __restrict__ srcl, int* __restrict__ rowptr,
    float* __restrict__ nmask, float* __restrict__ dinv) {
    __shared__ int hist[NPG];
    __shared__ int incl[512];
    __shared__ int cur[NPG];
    const int g = blockIdx.x, t = threadIdx.x;
    for (int i = t; i < NPG; i += 512) hist[i] = 0;
    __syncthreads();
    for (int e = t; e < EPG; e += 512)
        atomicAdd(&hist[dst[g * EPG + e] - g * NPG], 1);
    __syncthreads();
    incl[t] = (t < NPG) ? hist[t] : 0;
    __syncthreads();
    for (int off = 1; off < 512; off <<= 1) {
        int add = (t >= off) ? incl[t - off] : 0;
        __syncthreads();
        incl[t] += add;
        __syncthreads();
    }
    if (t < NPG) {
        rowptr[g * (NPG + 1) + t + 1] = incl[t];
        cur[t] = incl[t] - hist[t];
        nmask[g * NPG + t] = 1.0f;
        dinv[g * NPG + t] = rsqrtf(1.0f + (float)hist[t]);  // all nodes active in layer 1
    }
    if (t == 0) rowptr[g * (NPG + 1)] = 0;
    __syncthreads();
    for (int e = t; e < EPG; e += 512) {
        int dl = dst[g * EPG + e] - g * NPG;
        int pos = atomicAdd(&cur[dl], 1);
        srcl[g * EPG + pos] = (unsigned short)(src[g * EPG + e] - g * NPG);
    }
}

// --------------------------------------------------------------------- GEMM
// H = X @ W (64 rows / 256-thread block). EPI: fuse relu(H+b)*nmask.
template<int IN, int OUT, bool EPI>
__global__ __launch_bounds__(256) void gemm_kernel(
    const float* __restrict__ X, const float* __restrict__ W,
    const float* __restrict__ bias, const float* __restrict__ nmask,
    float* __restrict__ H) {
    __shared__ float sX[64 * IN];
    const int row0 = blockIdx.x * 64;
    const int t = threadIdx.x;
    for (int i = t; i < 64 * IN; i += 256) sX[i] = X[(size_t)row0 * IN + i];
    __syncthreads();
    constexpr int GROUPS = 256 / OUT;   // 8,4,2
    constexpr int RPT    = 64 / GROUPS; // 8,16,32
    const int c  = t % OUT;
    const int r0 = (t / OUT) * RPT;
    float acc[RPT];
#pragma unroll
    for (int rr = 0; rr < RPT; rr++) acc[rr] = 0.0f;
    for (int j4 = 0; j4 < IN / 4; j4++) {
        const float w0 = W[(j4 * 4 + 0) * OUT + c];
        const float w1 = W[(j4 * 4 + 1) * OUT + c];
        const float w2 = W[(j4 * 4 + 2) * OUT + c];
        const float w3 = W[(j4 * 4 + 3) * OUT + c];
#pragma unroll
        for (int rr = 0; rr < RPT; rr++) {
            const float4 xv = *reinterpret_cast<const float4*>(&sX[(r0 + rr) * IN + j4 * 4]);
            acc[rr] += xv.x * w0 + xv.y * w1 + xv.z * w2 + xv.w * w3;
        }
    }
#pragma unroll
    for (int rr = 0; rr < RPT; rr++) {
        const int r = row0 + r0 + rr;
        float v = acc[rr];
        if (EPI) v = fmaxf(v + bias[c], 0.0f) * nmask[r];
        H[(size_t)r * OUT + c] = v;
    }
}

// ---------------------------------------------------------------- aggregate
// Out[n] = sum_{e:dst=n} H[src_e]*dinv[src_e]*dinv[n] + H[n]*dinv[n]^2,
// 32-feature chunks, all-LDS CSR gather, 4x edge unroll.
// EPI: fuse relu(.+b)*nmask (used when agg runs after the GEMM).
template<int OUT, int NCH, int NS, bool EPI>
__global__ __launch_bounds__(512) void gcn_agg_kernel(
    const float* __restrict__ H, float* __restrict__ Y,
    const float* __restrict__ dinv, const float* __restrict__ nmask,
    const float* __restrict__ bias,
    const unsigned short* __restrict__ srcl, const int* __restrict__ rowptr) {
    __shared__ float Hl[NPG * 32];
    __shared__ float dinvl[NPG];
    __shared__ unsigned short sl[EPG];
    __shared__ int rp[NPG + 1];
    const int b   = blockIdx.x;
    const int g   = b / (NCH * NS);
    const int rem = b % (NCH * NS);
    const int f0  = (rem / NS) * 32;
    const int n0  = (rem % NS) * (NPG / NS);
    const int t   = threadIdx.x;

    for (int i = t; i < NPG; i += 512) dinvl[i] = dinv[g * NPG + i];
    for (int i = t; i <= NPG; i += 512) rp[i] = rowptr[g * (NPG + 1) + i];
    for (int i = t; i < EPG / 2; i += 512)
        reinterpret_cast<unsigned int*>(sl)[i] =
            reinterpret_cast<const unsigned int*>(srcl + g * EPG)[i];
    if (OUT == 32) {
        for (int i = t; i < NPG * 8; i += 512)
            reinterpret_cast<float4*>(Hl)[i] =
                reinterpret_cast<const float4*>(H + (size_t)g * NPG * 32)[i];
    } else {
        for (int i = t; i < NPG * 8; i += 512) {
            int n = i >> 3, q = i & 7;
            reinterpret_cast<float4*>(Hl)[i] =
                *reinterpret_cast<const float4*>(&H[(size_t)(g * NPG + n) * OUT + f0 + q * 4]);
        }
    }
    __syncthreads();

    const int wave = t >> 6, lane = t & 63;
    const int slot = wave * 2 + (lane >> 5);  // 0..15
    const int f    = lane & 31;
    const float bv = EPI ? bias[f0 + f] : 0.0f;
    constexpr int NPB = NPG / NS;
    for (int n = n0 + slot; n < n0 + NPB; n += 16) {
        const float di = dinvl[n];
        const int e1 = rp[n + 1];
        int e = rp[n];
        float a0 = 0.f, a1 = 0.f, a2 = 0.f, a3 = 0.f;
        for (; e + 4 <= e1; e += 4) {
            const int s0 = sl[e], s1 = sl[e + 1], s2 = sl[e + 2], s3 = sl[e + 3];
            a0 += Hl[s0 * 32 + f] * dinvl[s0];
            a1 += Hl[s1 * 32 + f] * dinvl[s1];
            a2 += Hl[s2 * 32 + f] * dinvl[s2];
            a3 += Hl[s3 * 32 + f] * dinvl[s3];
        }
        for (; e < e1; e++) { const int s = sl[e]; a0 += Hl[s * 32 + f] * dinvl[s]; }
        float acc = ((a0 + a1) + (a2 + a3)) * di + Hl[n * 32 + f] * (di * di);
        if (EPI) acc = fmaxf(acc + bv, 0.0f) * nmask[g * NPG + n];
        Y[(size_t)(g * NPG + n) * OUT + f0 + f] = acc;
    }
}

// ------------------------------------------------------------------- top-k
// One block per graph. Bitonic sort, (value desc, index asc) order — exact
// lax.top_k set semantics. Also rebuilds nmask AND computes next-layer dinv.
template<int DIM>
__global__ __launch_bounds__(512) void topk_kernel(
    float* __restrict__ X, float* __restrict__ nmask, float* __restrict__ dinv,
    const float* __restrict__ p, int K,
    const unsigned short* __restrict__ srcl, const int* __restrict__ rowptr) {
    __shared__ float sval[512];
    __shared__ int   sidx[512];
    __shared__ float sscore[NPG];
    __shared__ float nml[NPG];
    __shared__ unsigned short sl[EPG];
    __shared__ int rp[NPG + 1];
    __shared__ float spnorm;
    const int g = blockIdx.x;
    const int t = threadIdx.x;
    for (int i = t; i < EPG / 2; i += 512)
        reinterpret_cast<unsigned int*>(sl)[i] =
            reinterpret_cast<const unsigned int*>(srcl + g * EPG)[i];
    for (int i = t; i <= NPG; i += 512) rp[i] = rowptr[g * (NPG + 1) + i];
    if (t == 0) {
        float s = 0.0f;
        for (int j = 0; j < DIM; j++) s += p[j] * p[j];
        spnorm = sqrtf(s);
    }
    __syncthreads();
    if (t < NPG) {
        const float* xr = X + (size_t)(g * NPG + t) * DIM;
        float s = 0.0f;
        for (int j4 = 0; j4 < DIM / 4; j4++) {
            float4 xv = *reinterpret_cast<const float4*>(&xr[j4 * 4]);
            float4 pv = *reinterpret_cast<const float4*>(&p[j4 * 4]);
            s += xv.x * pv.x + xv.y * pv.y + xv.z * pv.z + xv.w * pv.w;
        }
        s /= spnorm;
        sscore[t] = s;
        sval[t] = (nmask[g * NPG + t] > 0.0f) ? s : -INFINITY;
        sidx[t] = t;
    } else {
        sval[t] = -INFINITY;
        sidx[t] = 0x7FFFFFFF;
    }
    __syncthreads();
    for (int kk = 2; kk <= 512; kk <<= 1) {
        for (int j = kk >> 1; j > 0; j >>= 1) {
            int l = t ^ j;
            if (l > t) {
                float va = sval[t], vb = sval[l];
                int   ia = sidx[t], ib = sidx[l];
                bool aFirst = (va > vb) || (va == vb && ia < ib);
                bool desc   = ((t & kk) == 0);
                if (desc != aFirst) {
                    sval[t] = vb; sval[l] = va;
                    sidx[t] = ib; sidx[l] = ia;
                }
            }
            __syncthreads();
        }
    }
    if (t < NPG) nml[t] = 0.0f;
    __syncthreads();
    if (t < K) nml[sidx[t]] = 1.0f;
    __syncthreads();
    if (t < NPG) nmask[g * NPG + t] = nml[t];
    // next-layer dinv from new mask
    for (int n = t; n < NPG; n += 512) {
        float d = 0.0f;
        if (nml[n] > 0.0f) {
            d = 1.0f;
            int e = rp[n]; const int e1 = rp[n + 1];
            float d0 = 0.f, d1 = 0.f, d2 = 0.f, d3 = 0.f;
            for (; e + 4 <= e1; e += 4) {
                d0 += nml[sl[e]]; d1 += nml[sl[e + 1]];
                d2 += nml[sl[e + 2]]; d3 += nml[sl[e + 3]];
            }
            for (; e < e1; e++) d0 += nml[sl[e]];
            d += (d0 + d1) + (d2 + d3);
        }
        dinv[g * NPG + n] = (d > 0.0f) ? rsqrtf(d) : 0.0f;
    }
    // x *= tanh(score) * new_mask
    for (int i = t; i < NPG * DIM; i += 512) {
        int n = i / DIM;
        float fct = (nml[n] > 0.0f) ? tanhf(sscore[n]) : 0.0f;
        X[(size_t)g * NPG * DIM + i] *= fct;
    }
}

// --------------------------------------------------------------- max pool
__global__ void maxpool_kernel(const float* __restrict__ X, float* __restrict__ HP) {
    const int g = blockIdx.x;
    const int f = threadIdx.x; // 128
    const float* base = X + (size_t)g * NPG * 128 + f;
    float m = 0.0f; // post-relu values are >= 0
    for (int n = 0; n < NPG; n++) m = fmaxf(m, base[n * 128]);
    HP[g * 128 + f] = m;
}

// -------------------------------------------------------------------- head
// One block per output column (BN stats are column-local). 128 threads = rows.
template<int IN, int OUT>
__global__ __launch_bounds__(128) void head_layer_kernel(
    const float* __restrict__ A, const float* __restrict__ W,
    const float* __restrict__ b, const float* __restrict__ ga,
    const float* __restrict__ be, float* __restrict__ Y) {
    __shared__ float Al[128 * (IN + 1)];
    __shared__ float red[4];
    const int c = blockIdx.x, t = threadIdx.x;
    for (int i = t; i < 128 * IN; i += 128)
        Al[(i / IN) * (IN + 1) + (i % IN)] = A[i];
    __syncthreads();
    float acc = b[c];
#pragma unroll
    for (int j = 0; j < IN; j++) acc += Al[t * (IN + 1) + j] * W[j * OUT + c];
    float s1 = acc, s2 = acc * acc;
    for (int o = 32; o > 0; o >>= 1) {
        s1 += __shfl_down(s1, o, 64);
        s2 += __shfl_down(s2, o, 64);
    }
    if ((t & 63) == 0) { red[t >> 6] = s1; red[2 + (t >> 6)] = s2; }
    __syncthreads();
    const float S1 = red[0] + red[1], S2 = red[2] + red[3];
    const float m = S1 * (1.0f / 128.0f);
    const float var = S2 * (1.0f / 128.0f) - m * m;
    float val = ga[c] * (acc - m) * rsqrtf(var + 1e-5f) + be[c];
    Y[t * OUT + c] = fmaxf(val, 0.0f);
}

__global__ __launch_bounds__(128) void head_final_kernel(
    const float* __restrict__ A, const float* __restrict__ w,
    const float* __restrict__ b, float* __restrict__ out) {
    const int t = threadIdx.x; // 128
    float acc = b[0];
#pragma unroll
    for (int j = 0; j < 16; j++) acc += A[t * 16 + j] * w[j];
    out[t] = acc;
}

// ------------------------------------------------------------------ driver
extern "C" void kernel_launch(void* const* d_in, const int* in_sizes, int n_in,
                              void* d_out, int out_size, void* d_ws, size_t ws_size,
                              hipStream_t stream) {
    (void)in_sizes; (void)n_in; (void)out_size; (void)ws_size;
    const float* x   = (const float*)d_in[0];
    const int*   ei  = (const int*)d_in[1];
    const float* W1  = (const float*)d_in[3];  const float* b1  = (const float*)d_in[4];
    const float* W2  = (const float*)d_in[5];  const float* b2  = (const float*)d_in[6];
    const float* W3  = (const float*)d_in[7];  const float* b3  = (const float*)d_in[8];
    const float* W4  = (const float*)d_in[9];  const float* b4  = (const float*)d_in[10];
    const float* p1  = (const float*)d_in[11];
    const float* p2  = (const float*)d_in[12];
    const float* p3  = (const float*)d_in[13];
    const float* Lw1 = (const float*)d_in[14]; const float* Lb1 = (const float*)d_in[15];
    const float* Lw2 = (const float*)d_in[16]; const float* Lb2 = (const float*)d_in[17];
    const float* Lw3 = (const float*)d_in[18]; const float* Lb3 = (const float*)d_in[19];
    const float* Lw4 = (const float*)d_in[20]; const float* Lb4 = (const float*)d_in[21];
    const float* Lw5 = (const float*)d_in[22]; const float* Lb5 = (const float*)d_in[23];
    const float* g1  = (const float*)d_in[24]; const float* be1 = (const float*)d_in[25];
    const float* g2  = (const float*)d_in[26]; const float* be2 = (const float*)d_in[27];
    const float* g3  = (const float*)d_in[28]; const float* be3 = (const float*)d_in[29];
    const float* g4  = (const float*)d_in[30]; const float* be4 = (const float*)d_in[31];

    const int* src = ei;
    const int* dst = ei + NEDGES;

    float* ws    = (float*)d_ws;
    float* hb    = ws;                           // NNODES*128 (H or aggX)
    float* x0    = hb + (size_t)NNODES * 128;    // NNODES*128
    float* x1    = x0 + (size_t)NNODES * 128;    // NNODES*128
    float* nmask = x1 + (size_t)NNODES * 128;    // NNODES
    float* dinv  = nmask + NNODES;               // NNODES
    float* hp    = dinv + NNODES;                // 128*128
    float* a1    = hp + 128 * 128;               // 128*64
    float* a2    = a1 + 128 * 64;                // 128*64
    float* a3    = a2 + 128 * 64;                // 128*32
    float* a4    = a3 + 128 * 32;                // 128*16
    unsigned short* srcl = (unsigned short*)(a4 + 128 * 16); // NEDGES u16
    int* rowptr  = (int*)(srcl + NEDGES);        // 128*(NPG+1)

    csr_build_kernel<<<BGRAPHS, 512, 0, stream>>>(src, dst, srcl, rowptr, nmask, dinv);

    // conv1 (64->32): gemm first (fewer feats after), agg with fused epilogue
    gemm_kernel<64, 32, false><<<NNODES / 64, 256, 0, stream>>>(x, W1, nullptr, nullptr, hb);
    gcn_agg_kernel<32, 1, 2, true><<<BGRAPHS * 2, 512, 0, stream>>>(hb, x0, dinv, nmask, b1, srcl, rowptr);
    topk_kernel<32><<<BGRAPHS, 512, 0, stream>>>(x0, nmask, dinv, p1, 360, srcl, rowptr);

    // conv2 (32->64): agg X first (32 feats), gemm with fused epilogue
    gcn_agg_kernel<32, 1, 2, false><<<BGRAPHS * 2, 512, 0, stream>>>(x0, hb, dinv, nmask, nullptr, srcl, rowptr);
    gemm_kernel<32, 64, true><<<NNODES / 64, 256, 0, stream>>>(hb, W2, b2, nmask, x1);
    topk_kernel<64><<<BGRAPHS, 512, 0, stream>>>(x1, nmask, dinv, p2, 324, srcl, rowptr);

    // conv3 (64->128): agg first (64 feats)
    gcn_agg_kernel<64, 2, 2, false><<<BGRAPHS * 4, 512, 0, stream>>>(x1, hb, dinv, nmask, nullptr, srcl, rowptr);
    gemm_kernel<64, 128, true><<<NNODES / 64, 256, 0, stream>>>(hb, W3, b3, nmask, x0);
    topk_kernel<128><<<BGRAPHS, 512, 0, stream>>>(x0, nmask, dinv, p3, 292, srcl, rowptr);

    // conv4 (128->128): agg first
    gcn_agg_kernel<128, 4, 1, false><<<BGRAPHS * 4, 512, 0, stream>>>(x0, hb, dinv, nmask, nullptr, srcl, rowptr);
    gemm_kernel<128, 128, true><<<NNODES / 64, 256, 0, stream>>>(hb, W4, b4, nmask, x1);

    maxpool_kernel<<<BGRAPHS, 128, 0, stream>>>(x1, hp);
    head_layer_kernel<128, 64><<<64, 128, 0, stream>>>(hp, Lw1, Lb1, g1, be1, a1);
    head_layer_kernel<64, 64><<<64, 128, 0, stream>>>(a1, Lw2, Lb2, g2, be2, a2);
    head_layer_kernel<64, 32><<<32, 128, 0, stream>>>(a2, Lw3, Lb3, g3, be3, a3);
    head_layer_kernel<32, 16><<<16, 128, 0, stream>>>(a3, Lw4, Lb4, g4, be4, a4);
    head_final_kernel<<<1, 128, 0, stream>>>(a4, Lw5, Lb5, (float*)d_out);
}

// Round 4
// 374.739 us; speedup vs baseline: 8.5440x; 1.2584x over previous
//
#include <hip/hip_runtime.h>
#include <math.h>

#define NNODES 51200
#define BGRAPHS 128
#define NPG 400
#define NEDGES 819200
#define EPG 6400   // edges per graph

// ---------------- CSR build (+ nmask=1, + dinv for layer 1) ----------------
// One block per graph. Parallel Hillis-Steele scan for rowptr.
__global__ __launch_bounds__(512) void csr_build_kernel(
    const int* __restrict__ src, const int* __restrict__ dst,
    unsigned short* __restrict__ srcl, int* __restrict__ rowptr,
    float* __restrict__ nmask, float* __restrict__ dinv) {
    __shared__ int hist[NPG];
    __shared__ int incl[512];
    __shared__ int cur[NPG];
    const int g = blockIdx.x, t = threadIdx.x;
    for (int i = t; i < NPG; i += 512) hist[i] = 0;
    __syncthreads();
    for (int e = t; e < EPG; e += 512)
        atomicAdd(&hist[dst[g * EPG + e] - g * NPG], 1);
    __syncthreads();
    incl[t] = (t < NPG) ? hist[t] : 0;
    __syncthreads();
    for (int off = 1; off < 512; off <<= 1) {
        int add = (t >= off) ? incl[t - off] : 0;
        __syncthreads();
        incl[t] += add;
        __syncthreads();
    }
    if (t < NPG) {
        rowptr[g * (NPG + 1) + t + 1] = incl[t];
        cur[t] = incl[t] - hist[t];
        nmask[g * NPG + t] = 1.0f;
        dinv[g * NPG + t] = rsqrtf(1.0f + (float)hist[t]);  // all nodes active in layer 1
    }
    if (t == 0) rowptr[g * (NPG + 1)] = 0;
    __syncthreads();
    for (int e = t; e < EPG; e += 512) {
        int dl = dst[g * EPG + e] - g * NPG;
        int pos = atomicAdd(&cur[dl], 1);
        srcl[g * EPG + pos] = (unsigned short)(src[g * EPG + e] - g * NPG);
    }
}

// --------------------------------------------------------------------- GEMM
// H = X @ W (64 rows / 256-thread block). EPI: fuse relu(H+b)*nmask.
template<int IN, int OUT, bool EPI>
__global__ __launch_bounds__(256) void gemm_kernel(
    const float* __restrict__ X, const float* __restrict__ W,
    const float* __restrict__ bias, const float* __restrict__ nmask,
    float* __restrict__ H) {
    __shared__ float sX[64 * IN];
    const int row0 = blockIdx.x * 64;
    const int t = threadIdx.x;
    for (int i = t; i < 64 * IN; i += 256) sX[i] = X[(size_t)row0 * IN + i];
    __syncthreads();
    constexpr int GROUPS = 256 / OUT;   // 8,4,2
    constexpr int RPT    = 64 / GROUPS; // 8,16,32
    const int c  = t % OUT;
    const int r0 = (t / OUT) * RPT;
    float acc[RPT];
#pragma unroll
    for (int rr = 0; rr < RPT; rr++) acc[rr] = 0.0f;
    for (int j4 = 0; j4 < IN / 4; j4++) {
        const float w0 = W[(j4 * 4 + 0) * OUT + c];
        const float w1 = W[(j4 * 4 + 1) * OUT + c];
        const float w2 = W[(j4 * 4 + 2) * OUT + c];
        const float w3 = W[(j4 * 4 + 3) * OUT + c];
#pragma unroll
        for (int rr = 0; rr < RPT; rr++) {
            const float4 xv = *reinterpret_cast<const float4*>(&sX[(r0 + rr) * IN + j4 * 4]);
            acc[rr] += xv.x * w0 + xv.y * w1 + xv.z * w2 + xv.w * w3;
        }
    }
#pragma unroll
    for (int rr = 0; rr < RPT; rr++) {
        const int r = row0 + r0 + rr;
        float v = acc[rr];
        if (EPI) v = fmaxf(v + bias[c], 0.0f) * nmask[r];
        H[(size_t)r * OUT + c] = v;
    }
}

// ---------------------------------------------------------------- aggregate
// Out[n] = sum_{e:dst=n} Hs[src_e]*dinv[src_e]*dinv[n] + Hs[n]*dinv[n]^2,
// where Hs = H * fct (per-node factor from the preceding top-k pool, if FCT).
// 32-feature chunks, all-LDS CSR gather, 4x edge unroll.
// EPI: fuse relu(.+b)*nmask (used when agg runs after the GEMM).
template<int OUT, int NCH, int NS, bool EPI, bool FCT>
__global__ __launch_bounds__(512) void gcn_agg_kernel(
    const float* __restrict__ H, float* __restrict__ Y,
    const float* __restrict__ dinv, const float* __restrict__ nmask,
    const float* __restrict__ bias, const float* __restrict__ fct,
    const unsigned short* __restrict__ srcl, const int* __restrict__ rowptr) {
    __shared__ float Hl[NPG * 32];
    __shared__ float dinvl[NPG];
    __shared__ unsigned short sl[EPG];
    __shared__ int rp[NPG + 1];
    const int b   = blockIdx.x;
    const int g   = b / (NCH * NS);
    const int rem = b % (NCH * NS);
    const int f0  = (rem / NS) * 32;
    const int n0  = (rem % NS) * (NPG / NS);
    const int t   = threadIdx.x;

    for (int i = t; i < NPG; i += 512) dinvl[i] = dinv[g * NPG + i];
    for (int i = t; i <= NPG; i += 512) rp[i] = rowptr[g * (NPG + 1) + i];
    for (int i = t; i < EPG / 2; i += 512)
        reinterpret_cast<unsigned int*>(sl)[i] =
            reinterpret_cast<const unsigned int*>(srcl + g * EPG)[i];
    for (int i = t; i < NPG * 8; i += 512) {
        int n = i >> 3, q = i & 7;
        float4 v = *reinterpret_cast<const float4*>(&H[(size_t)(g * NPG + n) * OUT + f0 + q * 4]);
        if (FCT) {
            float s = fct[g * NPG + n];
            v.x *= s; v.y *= s; v.z *= s; v.w *= s;
        }
        reinterpret_cast<float4*>(Hl)[i] = v;
    }
    __syncthreads();

    const int wave = t >> 6, lane = t & 63;
    const int slot = wave * 2 + (lane >> 5);  // 0..15
    const int f    = lane & 31;
    const float bv = EPI ? bias[f0 + f] : 0.0f;
    constexpr int NPB = NPG / NS;
    for (int n = n0 + slot; n < n0 + NPB; n += 16) {
        const float di = dinvl[n];
        const int e1 = rp[n + 1];
        int e = rp[n];
        float a0 = 0.f, a1 = 0.f, a2 = 0.f, a3 = 0.f;
        for (; e + 4 <= e1; e += 4) {
            const int s0 = sl[e], s1 = sl[e + 1], s2 = sl[e + 2], s3 = sl[e + 3];
            a0 += Hl[s0 * 32 + f] * dinvl[s0];
            a1 += Hl[s1 * 32 + f] * dinvl[s1];
            a2 += Hl[s2 * 32 + f] * dinvl[s2];
            a3 += Hl[s3 * 32 + f] * dinvl[s3];
        }
        for (; e < e1; e++) { const int s = sl[e]; a0 += Hl[s * 32 + f] * dinvl[s]; }
        float acc = ((a0 + a1) + (a2 + a3)) * di + Hl[n * 32 + f] * (di * di);
        if (EPI) acc = fmaxf(acc + bv, 0.0f) * nmask[g * NPG + n];
        Y[(size_t)(g * NPG + n) * OUT + f0 + f] = acc;
    }
}

// ------------------------------------------------------------------- top-k
// One block per graph. Bitonic sort, (value desc, index asc) order — exact
// lax.top_k set semantics. Emits new nmask, next-layer dinv, and the per-node
// scale factor fct = tanh(score)*mask (applied lazily by the next agg).
template<int DIM>
__global__ __launch_bounds__(512) void topk_kernel(
    const float* __restrict__ X, float* __restrict__ nmask,
    float* __restrict__ dinv, float* __restrict__ fct,
    const float* __restrict__ p, int K,
    const unsigned short* __restrict__ srcl, const int* __restrict__ rowptr) {
    __shared__ float sval[512];
    __shared__ int   sidx[512];
    __shared__ float sscore[NPG];
    __shared__ float nml[NPG];
    __shared__ unsigned short sl[EPG];
    __shared__ int rp[NPG + 1];
    __shared__ float spnorm;
    const int g = blockIdx.x;
    const int t = threadIdx.x;
    for (int i = t; i < EPG / 2; i += 512)
        reinterpret_cast<unsigned int*>(sl)[i] =
            reinterpret_cast<const unsigned int*>(srcl + g * EPG)[i];
    for (int i = t; i <= NPG; i += 512) rp[i] = rowptr[g * (NPG + 1) + i];
    if (t == 0) {
        float s = 0.0f;
        for (int j = 0; j < DIM; j++) s += p[j] * p[j];
        spnorm = sqrtf(s);
    }
    __syncthreads();
    if (t < NPG) {
        const float* xr = X + (size_t)(g * NPG + t) * DIM;
        float s = 0.0f;
        for (int j4 = 0; j4 < DIM / 4; j4++) {
            float4 xv = *reinterpret_cast<const float4*>(&xr[j4 * 4]);
            float4 pv = *reinterpret_cast<const float4*>(&p[j4 * 4]);
            s += xv.x * pv.x + xv.y * pv.y + xv.z * pv.z + xv.w * pv.w;
        }
        s /= spnorm;
        sscore[t] = s;
        sval[t] = (nmask[g * NPG + t] > 0.0f) ? s : -INFINITY;
        sidx[t] = t;
    } else {
        sval[t] = -INFINITY;
        sidx[t] = 0x7FFFFFFF;
    }
    __syncthreads();
    for (int kk = 2; kk <= 512; kk <<= 1) {
        for (int j = kk >> 1; j > 0; j >>= 1) {
            int l = t ^ j;
            if (l > t) {
                float va = sval[t], vb = sval[l];
                int   ia = sidx[t], ib = sidx[l];
                bool aFirst = (va > vb) || (va == vb && ia < ib);
                bool desc   = ((t & kk) == 0);
                if (desc != aFirst) {
                    sval[t] = vb; sval[l] = va;
                    sidx[t] = ib; sidx[l] = ia;
                }
            }
            __syncthreads();
        }
    }
    if (t < NPG) nml[t] = 0.0f;
    __syncthreads();
    if (t < K) nml[sidx[t]] = 1.0f;
    __syncthreads();
    if (t < NPG) {
        nmask[g * NPG + t] = nml[t];
        fct[g * NPG + t] = (nml[t] > 0.0f) ? tanhf(sscore[t]) : 0.0f;
    }
    // next-layer dinv from new mask
    for (int n = t; n < NPG; n += 512) {
        float d = 0.0f;
        if (nml[n] > 0.0f) {
            d = 1.0f;
            int e = rp[n]; const int e1 = rp[n + 1];
            float d0 = 0.f, d1 = 0.f, d2 = 0.f, d3 = 0.f;
            for (; e + 4 <= e1; e += 4) {
                d0 += nml[sl[e]]; d1 += nml[sl[e + 1]];
                d2 += nml[sl[e + 2]]; d3 += nml[sl[e + 3]];
            }
            for (; e < e1; e++) d0 += nml[sl[e]];
            d += (d0 + d1) + (d2 + d3);
        }
        dinv[g * NPG + n] = (d > 0.0f) ? rsqrtf(d) : 0.0f;
    }
}

// --------------------------------------------------------------- max pool
// grid = BGRAPHS*4 (graph, node-quarter), block 256 = (2 nodes x 128 cols).
// Values are post-relu (>=0), HP zero-initialized -> atomicMax on uint bits.
__global__ __launch_bounds__(256) void maxpool_kernel(const float* __restrict__ X,
                                                      float* __restrict__ HP) {
    __shared__ float sm[128];
    const int b = blockIdx.x, g = b >> 2, q = b & 3;
    const int t = threadIdx.x, n2 = t >> 7, c = t & 127;
    const float* base = X + ((size_t)g * NPG + q * 100) * 128 + c;
    float m = 0.0f;
    for (int n = n2; n < 100; n += 2) m = fmaxf(m, base[(size_t)n * 128]);
    if (n2 == 0) sm[c] = m;
    __syncthreads();
    if (n2 == 1) sm[c] = fmaxf(sm[c], m);
    __syncthreads();
    if (n2 == 0)
        atomicMax(reinterpret_cast<unsigned int*>(&HP[g * 128 + c]), __float_as_uint(sm[c]));
}

// -------------------------------------------------------------------- head
// One block per output column (BN stats are column-local). 128 threads = rows.
template<int IN, int OUT>
__global__ __launch_bounds__(128) void head_layer_kernel(
    const float* __restrict__ A, const float* __restrict__ W,
    const float* __restrict__ b, const float* __restrict__ ga,
    const float* __restrict__ be, float* __restrict__ Y) {
    __shared__ float Al[128 * (IN + 1)];
    __shared__ float red[4];
    const int c = blockIdx.x, t = threadIdx.x;
    for (int i = t; i < 128 * IN; i += 128)
        Al[(i / IN) * (IN + 1) + (i % IN)] = A[i];
    __syncthreads();
    float acc = b[c];
#pragma unroll
    for (int j = 0; j < IN; j++) acc += Al[t * (IN + 1) + j] * W[j * OUT + c];
    float s1 = acc, s2 = acc * acc;
    for (int o = 32; o > 0; o >>= 1) {
        s1 += __shfl_down(s1, o, 64);
        s2 += __shfl_down(s2, o, 64);
    }
    if ((t & 63) == 0) { red[t >> 6] = s1; red[2 + (t >> 6)] = s2; }
    __syncthreads();
    const float S1 = red[0] + red[1], S2 = red[2] + red[3];
    const float m = S1 * (1.0f / 128.0f);
    const float var = S2 * (1.0f / 128.0f) - m * m;
    float val = ga[c] * (acc - m) * rsqrtf(var + 1e-5f) + be[c];
    Y[t * OUT + c] = fmaxf(val, 0.0f);
}

__global__ __launch_bounds__(128) void head_final_kernel(
    const float* __restrict__ A, const float* __restrict__ w,
    const float* __restrict__ b, float* __restrict__ out) {
    const int t = threadIdx.x; // 128
    float acc = b[0];
#pragma unroll
    for (int j = 0; j < 16; j++) acc += A[t * 16 + j] * w[j];
    out[t] = acc;
}

// ------------------------------------------------------------------ driver
extern "C" void kernel_launch(void* const* d_in, const int* in_sizes, int n_in,
                              void* d_out, int out_size, void* d_ws, size_t ws_size,
                              hipStream_t stream) {
    (void)in_sizes; (void)n_in; (void)out_size; (void)ws_size;
    const float* x   = (const float*)d_in[0];
    const int*   ei  = (const int*)d_in[1];
    const float* W1  = (const float*)d_in[3];  const float* b1  = (const float*)d_in[4];
    const float* W2  = (const float*)d_in[5];  const float* b2  = (const float*)d_in[6];
    const float* W3  = (const float*)d_in[7];  const float* b3  = (const float*)d_in[8];
    const float* W4  = (const float*)d_in[9];  const float* b4  = (const float*)d_in[10];
    const float* p1  = (const float*)d_in[11];
    const float* p2  = (const float*)d_in[12];
    const float* p3  = (const float*)d_in[13];
    const float* Lw1 = (const float*)d_in[14]; const float* Lb1 = (const float*)d_in[15];
    const float* Lw2 = (const float*)d_in[16]; const float* Lb2 = (const float*)d_in[17];
    const float* Lw3 = (const float*)d_in[18]; const float* Lb3 = (const float*)d_in[19];
    const float* Lw4 = (const float*)d_in[20]; const float* Lb4 = (const float*)d_in[21];
    const float* Lw5 = (const float*)d_in[22]; const float* Lb5 = (const float*)d_in[23];
    const float* g1  = (const float*)d_in[24]; const float* be1 = (const float*)d_in[25];
    const float* g2  = (const float*)d_in[26]; const float* be2 = (const float*)d_in[27];
    const float* g3  = (const float*)d_in[28]; const float* be3 = (const float*)d_in[29];
    const float* g4  = (const float*)d_in[30]; const float* be4 = (const float*)d_in[31];

    const int* src = ei;
    const int* dst = ei + NEDGES;

    float* ws    = (float*)d_ws;
    float* hb    = ws;                           // NNODES*128 (H or aggX)
    float* x0    = hb + (size_t)NNODES * 128;    // NNODES*128
    float* x1    = x0 + (size_t)NNODES * 128;    // NNODES*128
    float* nmask = x1 + (size_t)NNODES * 128;    // NNODES
    float* dinv  = nmask + NNODES;               // NNODES
    float* fct   = dinv + NNODES;                // NNODES
    float* hp    = fct + NNODES;                 // 128*128
    float* a1    = hp + 128 * 128;               // 128*64
    float* a2    = a1 + 128 * 64;                // 128*64
    float* a3    = a2 + 128 * 64;                // 128*32
    float* a4    = a3 + 128 * 32;                // 128*16
    unsigned short* srcl = (unsigned short*)(a4 + 128 * 16); // NEDGES u16
    int* rowptr  = (int*)(srcl + NEDGES);        // 128*(NPG+1)

    csr_build_kernel<<<BGRAPHS, 512, 0, stream>>>(src, dst, srcl, rowptr, nmask, dinv);

    // conv1 (64->32): gemm first (fewer feats after), agg with fused epilogue
    gemm_kernel<64, 32, false><<<NNODES / 64, 256, 0, stream>>>(x, W1, nullptr, nullptr, hb);
    gcn_agg_kernel<32, 1, 2, true, false><<<BGRAPHS * 2, 512, 0, stream>>>(hb, x0, dinv, nmask, b1, nullptr, srcl, rowptr);
    topk_kernel<32><<<BGRAPHS, 512, 0, stream>>>(x0, nmask, dinv, fct, p1, 360, srcl, rowptr);

    // conv2 (32->64): agg (x0*fct) first (32 feats), gemm with fused epilogue
    gcn_agg_kernel<32, 1, 2, false, true><<<BGRAPHS * 2, 512, 0, stream>>>(x0, hb, dinv, nmask, nullptr, fct, srcl, rowptr);
    gemm_kernel<32, 64, true><<<NNODES / 64, 256, 0, stream>>>(hb, W2, b2, nmask, x1);
    topk_kernel<64><<<BGRAPHS, 512, 0, stream>>>(x1, nmask, dinv, fct, p2, 324, srcl, rowptr);

    // conv3 (64->128): agg (x1*fct) first (64 feats)
    gcn_agg_kernel<64, 2, 2, false, true><<<BGRAPHS * 4, 512, 0, stream>>>(x1, hb, dinv, nmask, nullptr, fct, srcl, rowptr);
    gemm_kernel<64, 128, true><<<NNODES / 64, 256, 0, stream>>>(hb, W3, b3, nmask, x0);
    topk_kernel<128><<<BGRAPHS, 512, 0, stream>>>(x0, nmask, dinv, fct, p3, 292, srcl, rowptr);

    // conv4 (128->128): agg (x0*fct) first
    gcn_agg_kernel<128, 4, 1, false, true><<<BGRAPHS * 4, 512, 0, stream>>>(x0, hb, dinv, nmask, nullptr, fct, srcl, rowptr);
    gemm_kernel<128, 128, true><<<NNODES / 64, 256, 0, stream>>>(hb, W4, b4, nmask, x1);

    hipMemsetAsync(hp, 0, 128 * 128 * sizeof(float), stream);
    maxpool_kernel<<<BGRAPHS * 4, 256, 0, stream>>>(x1, hp);
    head_layer_kernel<128, 64><<<64, 128, 0, stream>>>(hp, Lw1, Lb1, g1, be1, a1);
    head_layer_kernel<64, 64><<<64, 128, 0, stream>>>(a1, Lw2, Lb2, g2, be2, a2);
    head_layer_kernel<64, 32><<<32, 128, 0, stream>>>(a2, Lw3, Lb3, g3, be3, a3);
    head_layer_kernel<32, 16><<<16, 128, 0, stream>>>(a3, Lw4, Lb4, g4, be4, a4);
    head_final_kernel<<<1, 128, 0, stream>>>(a4, Lw5, Lb5, (float*)d_out);
}

// Round 5
// 240.191 us; speedup vs baseline: 13.3302x; 1.5602x over previous
//
#include <hip/hip_runtime.h>
#include <math.h>

#define NNODES 51200
#define BGRAPHS 128
#define NPG 400
#define NEDGES 819200
#define EPG 6400    // edges per graph
#define SLP 7680    // padded src-list stride per graph (u16 entries, 1920 groups)

// ---------------- CSR build (padded 4-edge groups) ----------------
// One block per graph. Groups of 4 edges, node segments aligned to 4 entries,
// padded with idx=NPG (zero row). Also inits nmask=1, dinv=sc=rsqrt(1+deg).
__global__ __launch_bounds__(512) void csr_build_kernel(
    const int* __restrict__ src, const int* __restrict__ dst,
    unsigned short* __restrict__ slg, int* __restrict__ gsg, int* __restrict__ gcg,
    float* __restrict__ nmask, float* __restrict__ dinv, float* __restrict__ sc) {
    __shared__ int deg[NPG];
    __shared__ int incl[512];
    __shared__ int gs[NPG];
    __shared__ int cur[NPG];
    const int g = blockIdx.x, t = threadIdx.x;
    for (int i = t; i < NPG; i += 512) deg[i] = 0;
    __syncthreads();
    for (int e = t; e < EPG; e += 512)
        atomicAdd(&deg[dst[g * EPG + e] - g * NPG], 1);
    __syncthreads();
    const int d = (t < NPG) ? deg[t] : 0;
    const int p = (d + 3) >> 2;   // padded group count
    incl[t] = p;
    __syncthreads();
    for (int off = 1; off < 512; off <<= 1) {
        int add = (t >= off) ? incl[t - off] : 0;
        __syncthreads();
        incl[t] += add;
        __syncthreads();
    }
    if (t < NPG) {
        const int gstart = incl[t] - p;  // exclusive scan
        gs[t] = gstart;
        gsg[g * NPG + t] = gstart;
        gcg[g * NPG + t] = p;
        cur[t] = gstart * 4;
        nmask[g * NPG + t] = 1.0f;
        const float dv = rsqrtf(1.0f + (float)d);
        dinv[g * NPG + t] = dv;
        sc[g * NPG + t] = dv;
    }
    __syncthreads();
    for (int e = t; e < EPG; e += 512) {
        int dl = dst[g * EPG + e] - g * NPG;
        int pos = atomicAdd(&cur[dl], 1);
        slg[g * SLP + pos] = (unsigned short)(src[g * EPG + e] - g * NPG);
    }
    __syncthreads();
    if (t < NPG) {
        const int end = (gs[t] + p) * 4;
        for (int i = cur[t]; i < end; i++) slg[g * SLP + i] = (unsigned short)NPG;
    }
}

// --------------------------------------------------------------------- GEMM
// H = X @ W, register-tiled: thread = (col-group of 4, row-group of RPT).
// EPI: fuse relu(H+b)*nmask.
template<int IN, int OUT, bool EPI>
__global__ __launch_bounds__(256) void gemm_kernel(
    const float* __restrict__ X, const float* __restrict__ W,
    const float* __restrict__ bias, const float* __restrict__ nmask,
    float* __restrict__ H) {
    __shared__ __align__(16) float sX[64 * IN];
    const int row0 = blockIdx.x * 64;
    const int t = threadIdx.x;
    for (int i = t; i < 64 * IN / 4; i += 256)
        reinterpret_cast<float4*>(sX)[i] =
            reinterpret_cast<const float4*>(X + (size_t)row0 * IN)[i];
    __syncthreads();
    constexpr int CG  = OUT / 4;   // 8,16,32
    constexpr int RG  = 256 / CG;  // 32,16,8
    constexpr int RPT = 64 / RG;   // 2,4,8
    const int c0 = (t % CG) * 4;
    const int r0 = (t / CG) * RPT;
    float acc[RPT][4];
#pragma unroll
    for (int r = 0; r < RPT; r++)
#pragma unroll
        for (int j = 0; j < 4; j++) acc[r][j] = 0.0f;
    for (int k4 = 0; k4 < IN / 4; k4++) {
        const float4 w0 = *reinterpret_cast<const float4*>(&W[(k4 * 4 + 0) * OUT + c0]);
        const float4 w1 = *reinterpret_cast<const float4*>(&W[(k4 * 4 + 1) * OUT + c0]);
        const float4 w2 = *reinterpret_cast<const float4*>(&W[(k4 * 4 + 2) * OUT + c0]);
        const float4 w3 = *reinterpret_cast<const float4*>(&W[(k4 * 4 + 3) * OUT + c0]);
#pragma unroll
        for (int r = 0; r < RPT; r++) {
            const float4 xv = *reinterpret_cast<const float4*>(&sX[(r0 + r) * IN + k4 * 4]);
            acc[r][0] += xv.x * w0.x + xv.y * w1.x + xv.z * w2.x + xv.w * w3.x;
            acc[r][1] += xv.x * w0.y + xv.y * w1.y + xv.z * w2.y + xv.w * w3.y;
            acc[r][2] += xv.x * w0.z + xv.y * w1.z + xv.z * w2.z + xv.w * w3.z;
            acc[r][3] += xv.x * w0.w + xv.y * w1.w + xv.z * w2.w + xv.w * w3.w;
        }
    }
#pragma unroll
    for (int r = 0; r < RPT; r++) {
        const int row = row0 + r0 + r;
        float4 v = make_float4(acc[r][0], acc[r][1], acc[r][2], acc[r][3]);
        if (EPI) {
            const float4 b4 = *reinterpret_cast<const float4*>(&bias[c0]);
            const float m = nmask[row];
            v.x = fmaxf(v.x + b4.x, 0.0f) * m;
            v.y = fmaxf(v.y + b4.y, 0.0f) * m;
            v.z = fmaxf(v.z + b4.z, 0.0f) * m;
            v.w = fmaxf(v.w + b4.w, 0.0f) * m;
        }
        *reinterpret_cast<float4*>(&H[(size_t)row * OUT + c0]) = v;
    }
}

// ---------------------------------------------------------------- aggregate
// out[n] = dinv[n] * (Hs[n] + sum_{e:dst=n} Hs[src_e]),  Hs = H * sc
// (sc = fct*dinv folds pooling scale + edge norm; self-loop folds into sum).
// Lane layout: 8 sub-slots/wave x 8 lanes (float4 of 32-feat chunk).
template<int OUT, int NCH, int NS, bool EPI>
__global__ __launch_bounds__(512) void gcn_agg_kernel(
    const float* __restrict__ H, float* __restrict__ Y,
    const float* __restrict__ dinv, const float* __restrict__ sc,
    const float* __restrict__ bias,
    const unsigned short* __restrict__ slg, const int* __restrict__ gsg,
    const int* __restrict__ gcg) {
    __shared__ __align__(16) float Hl[(NPG + 1) * 36];
    __shared__ float dinvl[NPG];
    __shared__ int gsl[NPG];
    __shared__ int gcl[NPG];
    __shared__ unsigned long long sl64[SLP / 4];
    const unsigned short* sl = reinterpret_cast<const unsigned short*>(sl64);
    const int b   = blockIdx.x;
    const int g   = b / (NCH * NS);
    const int rem = b % (NCH * NS);
    const int f0  = (rem / NS) * 32;
    const int n0  = (rem % NS) * (NPG / NS);
    const int t   = threadIdx.x;

    for (int i = t; i < NPG; i += 512) {
        dinvl[i] = dinv[g * NPG + i];
        gsl[i] = gsg[g * NPG + i];
        gcl[i] = gcg[g * NPG + i];
    }
    for (int i = t; i < SLP / 4; i += 512)
        sl64[i] = reinterpret_cast<const unsigned long long*>(slg + (size_t)g * SLP)[i];
    if (t < 36) Hl[NPG * 36 + t] = 0.0f;   // zero row for pads
    for (int i = t; i < NPG * 8; i += 512) {
        const int n = i >> 3, q = i & 7;
        const float s = sc[g * NPG + n];
        float4 v = *reinterpret_cast<const float4*>(&H[(size_t)(g * NPG + n) * OUT + f0 + q * 4]);
        v.x *= s; v.y *= s; v.z *= s; v.w *= s;
        *reinterpret_cast<float4*>(&Hl[n * 36 + q * 4]) = v;
    }
    __syncthreads();

    const int wave = t >> 6, lane = t & 63;
    const int sub = lane >> 3, f4 = lane & 7;
    constexpr int NPB = NPG / NS;
    for (int n = n0 + wave * 8 + sub; n < n0 + NPB; n += 64) {
        const float di = dinvl[n];
        float* yp = &Y[(size_t)(g * NPG + n) * OUT + f0 + f4 * 4];
        if (di == 0.0f) {
            *reinterpret_cast<float4*>(yp) = make_float4(0.f, 0.f, 0.f, 0.f);
            continue;
        }
        const int g0 = gsl[n], g1 = g0 + gcl[n];
        float4 acc = *reinterpret_cast<const float4*>(&Hl[n * 36 + f4 * 4]);  // self
        for (int gg = g0; gg < g1; ++gg) {
            const unsigned long long q = *reinterpret_cast<const unsigned long long*>(&sl[gg * 4]);
            const int s0 = (int)(q & 0xFFFF), s1 = (int)((q >> 16) & 0xFFFF);
            const int s2 = (int)((q >> 32) & 0xFFFF), s3 = (int)(q >> 48);
            const float4 a = *reinterpret_cast<const float4*>(&Hl[s0 * 36 + f4 * 4]);
            const float4 bb = *reinterpret_cast<const float4*>(&Hl[s1 * 36 + f4 * 4]);
            const float4 c = *reinterpret_cast<const float4*>(&Hl[s2 * 36 + f4 * 4]);
            const float4 dd = *reinterpret_cast<const float4*>(&Hl[s3 * 36 + f4 * 4]);
            acc.x += (a.x + bb.x) + (c.x + dd.x);
            acc.y += (a.y + bb.y) + (c.y + dd.y);
            acc.z += (a.z + bb.z) + (c.z + dd.z);
            acc.w += (a.w + bb.w) + (c.w + dd.w);
        }
        acc.x *= di; acc.y *= di; acc.z *= di; acc.w *= di;
        if (EPI) {
            const float4 b4 = *reinterpret_cast<const float4*>(&bias[f0 + f4 * 4]);
            acc.x = fmaxf(acc.x + b4.x, 0.0f);
            acc.y = fmaxf(acc.y + b4.y, 0.0f);
            acc.z = fmaxf(acc.z + b4.z, 0.0f);
            acc.w = fmaxf(acc.w + b4.w, 0.0f);
        }
        *reinterpret_cast<float4*>(yp) = acc;
    }
}

// ------------------------------------------------------------------- top-k
// One block per graph. Bitonic sort, (value desc, index asc) order — exact
// lax.top_k set semantics. Emits new nmask, next-layer dinv, and
// sc = tanh(score)*mask*dinv (consumed by the next agg's staging).
template<int DIM>
__global__ __launch_bounds__(512) void topk_kernel(
    const float* __restrict__ X, float* __restrict__ nmask,
    float* __restrict__ dinv, float* __restrict__ sc,
    const float* __restrict__ p, int K,
    const unsigned short* __restrict__ slg, const int* __restrict__ gsg,
    const int* __restrict__ gcg) {
    __shared__ float sval[512];
    __shared__ int   sidx[512];
    __shared__ float sscore[NPG];
    __shared__ float nml[NPG + 1];
    __shared__ unsigned long long sl64[SLP / 4];
    __shared__ int gsl[NPG];
    __shared__ int gcl[NPG];
    __shared__ float spnorm;
    const unsigned short* sl = reinterpret_cast<const unsigned short*>(sl64);
    const int g = blockIdx.x;
    const int t = threadIdx.x;
    for (int i = t; i < SLP / 4; i += 512)
        sl64[i] = reinterpret_cast<const unsigned long long*>(slg + (size_t)g * SLP)[i];
    for (int i = t; i < NPG; i += 512) {
        gsl[i] = gsg[g * NPG + i];
        gcl[i] = gcg[g * NPG + i];
    }
    if (t == 0) {
        float s = 0.0f;
        for (int j = 0; j < DIM; j++) s += p[j] * p[j];
        spnorm = sqrtf(s);
    }
    __syncthreads();
    if (t < NPG) {
        const float* xr = X + (size_t)(g * NPG + t) * DIM;
        float s = 0.0f;
        for (int j4 = 0; j4 < DIM / 4; j4++) {
            float4 xv = *reinterpret_cast<const float4*>(&xr[j4 * 4]);
            float4 pv = *reinterpret_cast<const float4*>(&p[j4 * 4]);
            s += xv.x * pv.x + xv.y * pv.y + xv.z * pv.z + xv.w * pv.w;
        }
        s /= spnorm;
        sscore[t] = s;
        sval[t] = (nmask[g * NPG + t] > 0.0f) ? s : -INFINITY;
        sidx[t] = t;
    } else {
        sval[t] = -INFINITY;
        sidx[t] = 0x7FFFFFFF;
    }
    __syncthreads();
    for (int kk = 2; kk <= 512; kk <<= 1) {
        for (int j = kk >> 1; j > 0; j >>= 1) {
            int l = t ^ j;
            if (l > t) {
                float va = sval[t], vb = sval[l];
                int   ia = sidx[t], ib = sidx[l];
                bool aFirst = (va > vb) || (va == vb && ia < ib);
                bool desc   = ((t & kk) == 0);
                if (desc != aFirst) {
                    sval[t] = vb; sval[l] = va;
                    sidx[t] = ib; sidx[l] = ia;
                }
            }
            __syncthreads();
        }
    }
    if (t <= NPG) nml[t] = 0.0f;
    __syncthreads();
    if (t < K) nml[sidx[t]] = 1.0f;
    __syncthreads();
    if (t < NPG) nmask[g * NPG + t] = nml[t];
    // next-layer dinv + sc from new mask
    for (int n = t; n < NPG; n += 512) {
        float dv = 0.0f;
        if (nml[n] > 0.0f) {
            float d = 1.0f;
            const int g0 = gsl[n], g1 = g0 + gcl[n];
            for (int gg = g0; gg < g1; ++gg) {
                const unsigned long long q = *reinterpret_cast<const unsigned long long*>(&sl[gg * 4]);
                d += nml[(int)(q & 0xFFFF)] + nml[(int)((q >> 16) & 0xFFFF)] +
                     nml[(int)((q >> 32) & 0xFFFF)] + nml[(int)(q >> 48)];
            }
            dv = rsqrtf(d);
        }
        dinv[g * NPG + n] = dv;
        sc[g * NPG + n] = (nml[n] > 0.0f) ? tanhf(sscore[n]) * dv : 0.0f;
    }
}

// --------------------------------------------------------------- max pool
// One block per graph: 512 threads = 128 cols x 4 node-quarters, LDS combine.
__global__ __launch_bounds__(512) void maxpool_kernel(const float* __restrict__ X,
                                                      float* __restrict__ HP) {
    __shared__ float sm[512];
    const int g = blockIdx.x, t = threadIdx.x;
    const int c = t & 127, q = t >> 7;
    const float* base = X + ((size_t)g * NPG + q * 100) * 128 + c;
    float m = 0.0f;  // post-relu values >= 0
    for (int n = 0; n < 100; n++) m = fmaxf(m, base[(size_t)n * 128]);
    sm[t] = m;
    __syncthreads();
    if (q == 0)
        HP[g * 128 + c] = fmaxf(fmaxf(sm[c], sm[c + 128]), fmaxf(sm[c + 256], sm[c + 384]));
}

// -------------------------------------------------------------------- head
// One block per output column (BN stats are column-local). 128 threads = rows.
template<int IN, int OUT>
__global__ __launch_bounds__(128) void head_layer_kernel(
    const float* __restrict__ A, const float* __restrict__ W,
    const float* __restrict__ b, const float* __restrict__ ga,
    const float* __restrict__ be, float* __restrict__ Y) {
    __shared__ float Al[128 * (IN + 1)];
    __shared__ float red[4];
    const int c = blockIdx.x, t = threadIdx.x;
    for (int i = t; i < 128 * IN; i += 128)
        Al[(i / IN) * (IN + 1) + (i % IN)] = A[i];
    __syncthreads();
    float acc = b[c];
#pragma unroll
    for (int j = 0; j < IN; j++) acc += Al[t * (IN + 1) + j] * W[j * OUT + c];
    float s1 = acc, s2 = acc * acc;
    for (int o = 32; o > 0; o >>= 1) {
        s1 += __shfl_down(s1, o, 64);
        s2 += __shfl_down(s2, o, 64);
    }
    if ((t & 63) == 0) { red[t >> 6] = s1; red[2 + (t >> 6)] = s2; }
    __syncthreads();
    const float S1 = red[0] + red[1], S2 = red[2] + red[3];
    const float m = S1 * (1.0f / 128.0f);
    const float var = S2 * (1.0f / 128.0f) - m * m;
    float val = ga[c] * (acc - m) * rsqrtf(var + 1e-5f) + be[c];
    Y[t * OUT + c] = fmaxf(val, 0.0f);
}

__global__ __launch_bounds__(128) void head_final_kernel(
    const float* __restrict__ A, const float* __restrict__ w,
    const float* __restrict__ b, float* __restrict__ out) {
    const int t = threadIdx.x; // 128
    float acc = b[0];
#pragma unroll
    for (int j = 0; j < 16; j++) acc += A[t * 16 + j] * w[j];
    out[t] = acc;
}

// ------------------------------------------------------------------ driver
extern "C" void kernel_launch(void* const* d_in, const int* in_sizes, int n_in,
                              void* d_out, int out_size, void* d_ws, size_t ws_size,
                              hipStream_t stream) {
    (void)in_sizes; (void)n_in; (void)out_size; (void)ws_size;
    const float* x   = (const float*)d_in[0];
    const int*   ei  = (const int*)d_in[1];
    const float* W1  = (const float*)d_in[3];  const float* b1  = (const float*)d_in[4];
    const float* W2  = (const float*)d_in[5];  const float* b2  = (const float*)d_in[6];
    const float* W3  = (const float*)d_in[7];  const float* b3  = (const float*)d_in[8];
    const float* W4  = (const float*)d_in[9];  const float* b4  = (const float*)d_in[10];
    const float* p1  = (const float*)d_in[11];
    const float* p2  = (const float*)d_in[12];
    const float* p3  = (const float*)d_in[13];
    const float* Lw1 = (const float*)d_in[14]; const float* Lb1 = (const float*)d_in[15];
    const float* Lw2 = (const float*)d_in[16]; const float* Lb2 = (const float*)d_in[17];
    const float* Lw3 = (const float*)d_in[18]; const float* Lb3 = (const float*)d_in[19];
    const float* Lw4 = (const float*)d_in[20]; const float* Lb4 = (const float*)d_in[21];
    const float* Lw5 = (const float*)d_in[22]; const float* Lb5 = (const float*)d_in[23];
    const float* g1  = (const float*)d_in[24]; const float* be1 = (const float*)d_in[25];
    const float* g2  = (const float*)d_in[26]; const float* be2 = (const float*)d_in[27];
    const float* g3  = (const float*)d_in[28]; const float* be3 = (const float*)d_in[29];
    const float* g4  = (const float*)d_in[30]; const float* be4 = (const float*)d_in[31];

    const int* src = ei;
    const int* dst = ei + NEDGES;

    float* ws    = (float*)d_ws;
    float* hb    = ws;                           // NNODES*128
    float* x0    = hb + (size_t)NNODES * 128;    // NNODES*128
    float* x1    = x0 + (size_t)NNODES * 128;    // NNODES*128
    float* nmask = x1 + (size_t)NNODES * 128;    // NNODES
    float* dinv  = nmask + NNODES;               // NNODES
    float* sc    = dinv + NNODES;                // NNODES
    float* hp    = sc + NNODES;                  // 128*128
    float* a1    = hp + 128 * 128;               // 128*64
    float* a2    = a1 + 128 * 64;                // 128*64
    float* a3    = a2 + 128 * 64;                // 128*32
    float* a4    = a3 + 128 * 32;                // 128*16
    unsigned short* slg = (unsigned short*)(a4 + 128 * 16); // BGRAPHS*SLP u16
    int* gsg = (int*)(slg + (size_t)BGRAPHS * SLP);          // BGRAPHS*NPG
    int* gcg = gsg + (size_t)BGRAPHS * NPG;                  // BGRAPHS*NPG

    csr_build_kernel<<<BGRAPHS, 512, 0, stream>>>(src, dst, slg, gsg, gcg, nmask, dinv, sc);

    // conv1 (64->32): gemm first, agg with fused bias+relu (all nodes active)
    gemm_kernel<64, 32, false><<<NNODES / 64, 256, 0, stream>>>(x, W1, nullptr, nullptr, hb);
    gcn_agg_kernel<32, 1, 2, true><<<BGRAPHS * 2, 512, 0, stream>>>(hb, x0, dinv, sc, b1, slg, gsg, gcg);
    topk_kernel<32><<<BGRAPHS, 512, 0, stream>>>(x0, nmask, dinv, sc, p1, 360, slg, gsg, gcg);

    // conv2 (32->64): agg first (32 feats, pool scale folded into sc), gemm w/ epilogue
    gcn_agg_kernel<32, 1, 2, false><<<BGRAPHS * 2, 512, 0, stream>>>(x0, hb, dinv, sc, nullptr, slg, gsg, gcg);
    gemm_kernel<32, 64, true><<<NNODES / 64, 256, 0, stream>>>(hb, W2, b2, nmask, x1);
    topk_kernel<64><<<BGRAPHS, 512, 0, stream>>>(x1, nmask, dinv, sc, p2, 324, slg, gsg, gcg);

    // conv3 (64->128): agg first (64 feats)
    gcn_agg_kernel<64, 2, 2, false><<<BGRAPHS * 4, 512, 0, stream>>>(x1, hb, dinv, sc, nullptr, slg, gsg, gcg);
    gemm_kernel<64, 128, true><<<NNODES / 64, 256, 0, stream>>>(hb, W3, b3, nmask, x0);
    topk_kernel<128><<<BGRAPHS, 512, 0, stream>>>(x0, nmask, dinv, sc, p3, 292, slg, gsg, gcg);

    // conv4 (128->128): agg first
    gcn_agg_kernel<128, 4, 1, false><<<BGRAPHS * 4, 512, 0, stream>>>(x0, hb, dinv, sc, nullptr, slg, gsg, gcg);
    gemm_kernel<128, 128, true><<<NNODES / 64, 256, 0, stream>>>(hb, W4, b4, nmask, x1);

    maxpool_kernel<<<BGRAPHS, 512, 0, stream>>>(x1, hp);
    head_layer_kernel<128, 64><<<64, 128, 0, stream>>>(hp, Lw1, Lb1, g1, be1, a1);
    head_layer_kernel<64, 64><<<64, 128, 0, stream>>>(a1, Lw2, Lb2, g2, be2, a2);
    head_layer_kernel<64, 32><<<32, 128, 0, stream>>>(a2, Lw3, Lb3, g3, be3, a3);
    head_layer_kernel<32, 16><<<16, 128, 0, stream>>>(a3, Lw4, Lb4, g4, be4, a4);
    head_final_kernel<<<1, 128, 0, stream>>>(a4, Lw5, Lb5, (float*)d_out);
}

// Round 6
// 209.477 us; speedup vs baseline: 15.2847x; 1.1466x over previous
//
#include <hip/hip_runtime.h>
#include <math.h>

#define NNODES 51200
#define BGRAPHS 128
#define NPG 400
#define NEDGES 819200
#define EPG 6400    // edges per graph
#define SLP 7680    // padded src-list stride per graph (u16 entries, 1920 groups)

// ---------------- CSR build (padded 4-edge groups) ----------------
// One block per graph. Groups of 4 edges, node segments aligned to 4 entries,
// padded with idx=NPG (zero row). Inits nmask=1, dinv=sc=rsqrt(1+deg), hp=0.
__global__ __launch_bounds__(512) void csr_build_kernel(
    const int* __restrict__ src, const int* __restrict__ dst,
    unsigned short* __restrict__ slg, int* __restrict__ gsg, int* __restrict__ gcg,
    float* __restrict__ nmask, float* __restrict__ dinv, float* __restrict__ sc,
    float* __restrict__ hp) {
    __shared__ int deg[NPG];
    __shared__ int incl[512];
    __shared__ int gs[NPG];
    __shared__ int cur[NPG];
    const int g = blockIdx.x, t = threadIdx.x;
    for (int i = t; i < NPG; i += 512) deg[i] = 0;
    if (t < 128) hp[g * 128 + t] = 0.0f;   // zero-init for gemm4's fused maxpool
    __syncthreads();
    for (int e = t; e < EPG; e += 512)
        atomicAdd(&deg[dst[g * EPG + e] - g * NPG], 1);
    __syncthreads();
    const int d = (t < NPG) ? deg[t] : 0;
    const int p = (d + 3) >> 2;   // padded group count
    incl[t] = p;
    __syncthreads();
    for (int off = 1; off < 512; off <<= 1) {
        int add = (t >= off) ? incl[t - off] : 0;
        __syncthreads();
        incl[t] += add;
        __syncthreads();
    }
    if (t < NPG) {
        const int gstart = incl[t] - p;  // exclusive scan
        gs[t] = gstart;
        gsg[g * NPG + t] = gstart;
        gcg[g * NPG + t] = p;
        cur[t] = gstart * 4;
        nmask[g * NPG + t] = 1.0f;
        const float dv = rsqrtf(1.0f + (float)d);
        dinv[g * NPG + t] = dv;
        sc[g * NPG + t] = dv;
    }
    __syncthreads();
    for (int e = t; e < EPG; e += 512) {
        int dl = dst[g * EPG + e] - g * NPG;
        int pos = atomicAdd(&cur[dl], 1);
        slg[g * SLP + pos] = (unsigned short)(src[g * EPG + e] - g * NPG);
    }
    __syncthreads();
    if (t < NPG) {
        const int end = (gs[t] + p) * 4;
        for (int i = cur[t]; i < end; i++) slg[g * SLP + i] = (unsigned short)NPG;
    }
}

// --------------------------------------------------------------------- GEMM
// H = X @ W, register-tiled: thread = (col-group of 4, row-group of RPT).
// MODE 0: plain store. MODE 2: EPI relu(+b)*mask store + fused topk score
// (raw dot with p via shuffle tree). MODE 3: EPI, NO store, fused global
// max-pool into hp (per-graph per-col atomicMax; values >= 0).
template<int IN, int OUT, int MODE>
__global__ __launch_bounds__(256) void gemm_kernel(
    const float* __restrict__ X, const float* __restrict__ W,
    const float* __restrict__ bias, const float* __restrict__ nmask,
    float* __restrict__ H, const float* __restrict__ p,
    float* __restrict__ score, float* __restrict__ hp) {
    __shared__ __align__(16) float sX[64 * IN];
    __shared__ unsigned smax[256];   // [2][128] for MODE 3
    const int row0 = blockIdx.x * 64;
    const int t = threadIdx.x;
    for (int i = t; i < 64 * IN / 4; i += 256)
        reinterpret_cast<float4*>(sX)[i] =
            reinterpret_cast<const float4*>(X + (size_t)row0 * IN)[i];
    if (MODE == 3) smax[t] = 0u;
    __syncthreads();
    constexpr int CG  = OUT / 4;   // 8,16,32
    constexpr int RG  = 256 / CG;  // 32,16,8
    constexpr int RPT = 64 / RG;   // 2,4,8
    const int c0 = (t % CG) * 4;
    const int r0 = (t / CG) * RPT;
    float acc[RPT][4];
#pragma unroll
    for (int r = 0; r < RPT; r++)
#pragma unroll
        for (int j = 0; j < 4; j++) acc[r][j] = 0.0f;
    for (int k4 = 0; k4 < IN / 4; k4++) {
        const float4 w0 = *reinterpret_cast<const float4*>(&W[(k4 * 4 + 0) * OUT + c0]);
        const float4 w1 = *reinterpret_cast<const float4*>(&W[(k4 * 4 + 1) * OUT + c0]);
        const float4 w2 = *reinterpret_cast<const float4*>(&W[(k4 * 4 + 2) * OUT + c0]);
        const float4 w3 = *reinterpret_cast<const float4*>(&W[(k4 * 4 + 3) * OUT + c0]);
#pragma unroll
        for (int r = 0; r < RPT; r++) {
            const float4 xv = *reinterpret_cast<const float4*>(&sX[(r0 + r) * IN + k4 * 4]);
            acc[r][0] += xv.x * w0.x + xv.y * w1.x + xv.z * w2.x + xv.w * w3.x;
            acc[r][1] += xv.x * w0.y + xv.y * w1.y + xv.z * w2.y + xv.w * w3.y;
            acc[r][2] += xv.x * w0.z + xv.y * w1.z + xv.z * w2.z + xv.w * w3.z;
            acc[r][3] += xv.x * w0.w + xv.y * w1.w + xv.z * w2.w + xv.w * w3.w;
        }
    }
    const int graph0 = row0 / 400;
    const int bnd = (graph0 + 1) * 400;   // first row of next graph (MODE 3)
    float ps[RPT];
#pragma unroll
    for (int r = 0; r < RPT; r++) {
        const int row = row0 + r0 + r;
        float4 v = make_float4(acc[r][0], acc[r][1], acc[r][2], acc[r][3]);
        if (MODE >= 2) {
            const float4 b4 = *reinterpret_cast<const float4*>(&bias[c0]);
            const float m = nmask[row];
            v.x = fmaxf(v.x + b4.x, 0.0f) * m;
            v.y = fmaxf(v.y + b4.y, 0.0f) * m;
            v.z = fmaxf(v.z + b4.z, 0.0f) * m;
            v.w = fmaxf(v.w + b4.w, 0.0f) * m;
        }
        if (MODE != 3) *reinterpret_cast<float4*>(&H[(size_t)row * OUT + c0]) = v;
        if (MODE == 2) {
            const float4 p4 = *reinterpret_cast<const float4*>(&p[c0]);
            ps[r] = v.x * p4.x + v.y * p4.y + v.z * p4.z + v.w * p4.w;
        }
        if (MODE == 3) {
            const int seg = (row >= bnd) ? 1 : 0;
            const float mx = fmaxf(fmaxf(v.x, v.y), fmaxf(v.z, v.w));
            // per-col LDS max (4 cols per thread)
            atomicMax(&smax[seg * 128 + c0 + 0], __float_as_uint(v.x));
            atomicMax(&smax[seg * 128 + c0 + 1], __float_as_uint(v.y));
            atomicMax(&smax[seg * 128 + c0 + 2], __float_as_uint(v.z));
            atomicMax(&smax[seg * 128 + c0 + 3], __float_as_uint(v.w));
            (void)mx;
        }
    }
    if (MODE == 2) {
        // reduce across the CG col-threads (aligned lane groups of CG)
#pragma unroll
        for (int r = 0; r < RPT; r++) {
#pragma unroll
            for (int off = 1; off < CG; off <<= 1) ps[r] += __shfl_xor(ps[r], off);
        }
        if ((t % CG) == 0) {
#pragma unroll
            for (int r = 0; r < RPT; r++) score[row0 + r0 + r] = ps[r];
        }
    }
    if (MODE == 3) {
        __syncthreads();
        unsigned* hpu = reinterpret_cast<unsigned*>(hp);
        if (t < 128) atomicMax(&hpu[graph0 * 128 + t], smax[t]);
        const int graph1 = (row0 + 63) / 400;
        if (graph1 != graph0 && t < 128) atomicMax(&hpu[graph1 * 128 + t], smax[128 + t]);
    }
}

// ---------------------------------------------------------------- aggregate
// out[n] = dinv[n] * (Hs[n] + sum_{e:dst=n} Hs[src_e]),  Hs = H * sc
// (sc = fct*dinv folds pooling scale + edge norm; self-loop folds into sum).
// SCORE: also emit raw topk score (out . p) via 8-lane shuffle tree.
template<int OUT, int NCH, int NS, bool EPI, bool SCORE>
__global__ __launch_bounds__(512) void gcn_agg_kernel(
    const float* __restrict__ H, float* __restrict__ Y,
    const float* __restrict__ dinv, const float* __restrict__ sc,
    const float* __restrict__ bias, const float* __restrict__ p,
    float* __restrict__ score,
    const unsigned short* __restrict__ slg, const int* __restrict__ gsg,
    const int* __restrict__ gcg) {
    __shared__ __align__(16) float Hl[(NPG + 1) * 36];
    __shared__ float dinvl[NPG];
    __shared__ int gsl[NPG];
    __shared__ int gcl[NPG];
    __shared__ unsigned long long sl64[SLP / 4];
    const unsigned short* sl = reinterpret_cast<const unsigned short*>(sl64);
    const int b   = blockIdx.x;
    const int g   = b / (NCH * NS);
    const int rem = b % (NCH * NS);
    const int f0  = (rem / NS) * 32;
    const int n0  = (rem % NS) * (NPG / NS);
    const int t   = threadIdx.x;

    for (int i = t; i < NPG; i += 512) {
        dinvl[i] = dinv[g * NPG + i];
        gsl[i] = gsg[g * NPG + i];
        gcl[i] = gcg[g * NPG + i];
    }
    for (int i = t; i < SLP / 4; i += 512)
        sl64[i] = reinterpret_cast<const unsigned long long*>(slg + (size_t)g * SLP)[i];
    if (t < 36) Hl[NPG * 36 + t] = 0.0f;   // zero row for pads
    for (int i = t; i < NPG * 8; i += 512) {
        const int n = i >> 3, q = i & 7;
        const float s = sc[g * NPG + n];
        float4 v = *reinterpret_cast<const float4*>(&H[(size_t)(g * NPG + n) * OUT + f0 + q * 4]);
        v.x *= s; v.y *= s; v.z *= s; v.w *= s;
        *reinterpret_cast<float4*>(&Hl[n * 36 + q * 4]) = v;
    }
    __syncthreads();

    const int wave = t >> 6, lane = t & 63;
    const int sub = lane >> 3, f4 = lane & 7;
    constexpr int NPB = NPG / NS;
    for (int n = n0 + wave * 8 + sub; n < n0 + NPB; n += 64) {
        const float di = dinvl[n];
        if (di == 0.0f) continue;   // inactive: consumer masks stale rows
        const int g0 = gsl[n], g1 = g0 + gcl[n];
        float4 acc = *reinterpret_cast<const float4*>(&Hl[n * 36 + f4 * 4]);  // self
        for (int gg = g0; gg < g1; ++gg) {
            const unsigned long long q = *reinterpret_cast<const unsigned long long*>(&sl[gg * 4]);
            const int s0 = (int)(q & 0xFFFF), s1 = (int)((q >> 16) & 0xFFFF);
            const int s2 = (int)((q >> 32) & 0xFFFF), s3 = (int)(q >> 48);
            const float4 a = *reinterpret_cast<const float4*>(&Hl[s0 * 36 + f4 * 4]);
            const float4 bb = *reinterpret_cast<const float4*>(&Hl[s1 * 36 + f4 * 4]);
            const float4 c = *reinterpret_cast<const float4*>(&Hl[s2 * 36 + f4 * 4]);
            const float4 dd = *reinterpret_cast<const float4*>(&Hl[s3 * 36 + f4 * 4]);
            acc.x += (a.x + bb.x) + (c.x + dd.x);
            acc.y += (a.y + bb.y) + (c.y + dd.y);
            acc.z += (a.z + bb.z) + (c.z + dd.z);
            acc.w += (a.w + bb.w) + (c.w + dd.w);
        }
        acc.x *= di; acc.y *= di; acc.z *= di; acc.w *= di;
        if (EPI) {
            const float4 b4 = *reinterpret_cast<const float4*>(&bias[f0 + f4 * 4]);
            acc.x = fmaxf(acc.x + b4.x, 0.0f);
            acc.y = fmaxf(acc.y + b4.y, 0.0f);
            acc.z = fmaxf(acc.z + b4.z, 0.0f);
            acc.w = fmaxf(acc.w + b4.w, 0.0f);
        }
        *reinterpret_cast<float4*>(&Y[(size_t)(g * NPG + n) * OUT + f0 + f4 * 4]) = acc;
        if (SCORE) {
            const float4 p4 = *reinterpret_cast<const float4*>(&p[f4 * 4]);
            float part = acc.x * p4.x + acc.y * p4.y + acc.z * p4.z + acc.w * p4.w;
            part += __shfl_xor(part, 1);
            part += __shfl_xor(part, 2);
            part += __shfl_xor(part, 4);
            if (f4 == 0) score[g * NPG + n] = part;
        }
    }
}

// ------------------------------------------------------------------- top-k
// One block per graph. Consumes fused raw scores (x.p); selection on raw
// scores is identical to scaled (positive scale preserves order and ties).
// Bitonic sort, (value desc, index asc) — exact lax.top_k set semantics.
// Emits new nmask, next-layer dinv, and sc = tanh(score/||p||)*mask*dinv.
template<int DIM>
__global__ __launch_bounds__(512) void topk_kernel(
    const float* __restrict__ score, float* __restrict__ nmask,
    float* __restrict__ dinv, float* __restrict__ sc,
    const float* __restrict__ p, int K,
    const unsigned short* __restrict__ slg, const int* __restrict__ gsg,
    const int* __restrict__ gcg) {
    __shared__ float sval[512];
    __shared__ int   sidx[512];
    __shared__ float sraw[NPG];
    __shared__ float nml[NPG + 1];
    __shared__ unsigned long long sl64[SLP / 4];
    __shared__ int gsl[NPG];
    __shared__ int gcl[NPG];
    __shared__ float spnorm;
    const unsigned short* sl = reinterpret_cast<const unsigned short*>(sl64);
    const int g = blockIdx.x;
    const int t = threadIdx.x;
    for (int i = t; i < SLP / 4; i += 512)
        sl64[i] = reinterpret_cast<const unsigned long long*>(slg + (size_t)g * SLP)[i];
    for (int i = t; i < NPG; i += 512) {
        gsl[i] = gsg[g * NPG + i];
        gcl[i] = gcg[g * NPG + i];
    }
    if (t == 0) {
        float s = 0.0f;
        for (int j = 0; j < DIM; j++) s += p[j] * p[j];
        spnorm = sqrtf(s);
    }
    __syncthreads();
    if (t < NPG) {
        const float raw = score[g * NPG + t];
        sraw[t] = raw;
        sval[t] = (nmask[g * NPG + t] > 0.0f) ? raw : -INFINITY;
        sidx[t] = t;
    } else {
        sval[t] = -INFINITY;
        sidx[t] = 0x7FFFFFFF;
    }
    __syncthreads();
    for (int kk = 2; kk <= 512; kk <<= 1) {
        for (int j = kk >> 1; j > 0; j >>= 1) {
            int l = t ^ j;
            if (l > t) {
                float va = sval[t], vb = sval[l];
                int   ia = sidx[t], ib = sidx[l];
                bool aFirst = (va > vb) || (va == vb && ia < ib);
                bool desc   = ((t & kk) == 0);
                if (desc != aFirst) {
                    sval[t] = vb; sval[l] = va;
                    sidx[t] = ib; sidx[l] = ia;
                }
            }
            __syncthreads();
        }
    }
    if (t <= NPG) nml[t] = 0.0f;
    __syncthreads();
    if (t < K) nml[sidx[t]] = 1.0f;
    __syncthreads();
    if (t < NPG) nmask[g * NPG + t] = nml[t];
    // next-layer dinv + sc from new mask
    for (int n = t; n < NPG; n += 512) {
        float dv = 0.0f;
        if (nml[n] > 0.0f) {
            float d = 1.0f;
            const int g0 = gsl[n], g1 = g0 + gcl[n];
            for (int gg = g0; gg < g1; ++gg) {
                const unsigned long long q = *reinterpret_cast<const unsigned long long*>(&sl[gg * 4]);
                d += nml[(int)(q & 0xFFFF)] + nml[(int)((q >> 16) & 0xFFFF)] +
                     nml[(int)((q >> 32) & 0xFFFF)] + nml[(int)(q >> 48)];
            }
            dv = rsqrtf(d);
        }
        dinv[g * NPG + n] = dv;
        sc[g * NPG + n] = (nml[n] > 0.0f) ? tanhf(sraw[n] / spnorm) * dv : 0.0f;
    }
}

// -------------------------------------------------------------------- head
// One block per output column (BN stats are column-local). 128 threads = rows.
template<int IN, int OUT>
__global__ __launch_bounds__(128) void head_layer_kernel(
    const float* __restrict__ A, const float* __restrict__ W,
    const float* __restrict__ b, const float* __restrict__ ga,
    const float* __restrict__ be, float* __restrict__ Y) {
    __shared__ float Al[128 * (IN + 1)];
    __shared__ float red[4];
    const int c = blockIdx.x, t = threadIdx.x;
    for (int i = t; i < 128 * IN; i += 128)
        Al[(i / IN) * (IN + 1) + (i % IN)] = A[i];
    __syncthreads();
    float acc = b[c];
#pragma unroll
    for (int j = 0; j < IN; j++) acc += Al[t * (IN + 1) + j] * W[j * OUT + c];
    float s1 = acc, s2 = acc * acc;
    for (int o = 32; o > 0; o >>= 1) {
        s1 += __shfl_down(s1, o, 64);
        s2 += __shfl_down(s2, o, 64);
    }
    if ((t & 63) == 0) { red[t >> 6] = s1; red[2 + (t >> 6)] = s2; }
    __syncthreads();
    const float S1 = red[0] + red[1], S2 = red[2] + red[3];
    const float m = S1 * (1.0f / 128.0f);
    const float var = S2 * (1.0f / 128.0f) - m * m;
    float val = ga[c] * (acc - m) * rsqrtf(var + 1e-5f) + be[c];
    Y[t * OUT + c] = fmaxf(val, 0.0f);
}

__global__ __launch_bounds__(128) void head_final_kernel(
    const float* __restrict__ A, const float* __restrict__ w,
    const float* __restrict__ b, float* __restrict__ out) {
    const int t = threadIdx.x; // 128
    float acc = b[0];
#pragma unroll
    for (int j = 0; j < 16; j++) acc += A[t * 16 + j] * w[j];
    out[t] = acc;
}

// ------------------------------------------------------------------ driver
extern "C" void kernel_launch(void* const* d_in, const int* in_sizes, int n_in,
                              void* d_out, int out_size, void* d_ws, size_t ws_size,
                              hipStream_t stream) {
    (void)in_sizes; (void)n_in; (void)out_size; (void)ws_size;
    const float* x   = (const float*)d_in[0];
    const int*   ei  = (const int*)d_in[1];
    const float* W1  = (const float*)d_in[3];  const float* b1  = (const float*)d_in[4];
    const float* W2  = (const float*)d_in[5];  const float* b2  = (const float*)d_in[6];
    const float* W3  = (const float*)d_in[7];  const float* b3  = (const float*)d_in[8];
    const float* W4  = (const float*)d_in[9];  const float* b4  = (const float*)d_in[10];
    const float* p1  = (const float*)d_in[11];
    const float* p2  = (const float*)d_in[12];
    const float* p3  = (const float*)d_in[13];
    const float* Lw1 = (const float*)d_in[14]; const float* Lb1 = (const float*)d_in[15];
    const float* Lw2 = (const float*)d_in[16]; const float* Lb2 = (const float*)d_in[17];
    const float* Lw3 = (const float*)d_in[18]; const float* Lb3 = (const float*)d_in[19];
    const float* Lw4 = (const float*)d_in[20]; const float* Lb4 = (const float*)d_in[21];
    const float* Lw5 = (const float*)d_in[22]; const float* Lb5 = (const float*)d_in[23];
    const float* g1  = (const float*)d_in[24]; const float* be1 = (const float*)d_in[25];
    const float* g2  = (const float*)d_in[26]; const float* be2 = (const float*)d_in[27];
    const float* g3  = (const float*)d_in[28]; const float* be3 = (const float*)d_in[29];
    const float* g4  = (const float*)d_in[30]; const float* be4 = (const float*)d_in[31];

    const int* src = ei;
    const int* dst = ei + NEDGES;

    float* ws    = (float*)d_ws;
    float* hb    = ws;                           // NNODES*128
    float* x0    = hb + (size_t)NNODES * 128;    // NNODES*128
    float* x1    = x0 + (size_t)NNODES * 128;    // NNODES*128
    float* nmask = x1 + (size_t)NNODES * 128;    // NNODES
    float* dinv  = nmask + NNODES;               // NNODES
    float* sc    = dinv + NNODES;                // NNODES
    float* scoreb= sc + NNODES;                  // NNODES
    float* hp    = scoreb + NNODES;              // 128*128
    float* a1    = hp + 128 * 128;               // 128*64
    float* a2    = a1 + 128 * 64;                // 128*64
    float* a3    = a2 + 128 * 64;                // 128*32
    float* a4    = a3 + 128 * 32;                // 128*16
    unsigned short* slg = (unsigned short*)(a4 + 128 * 16); // BGRAPHS*SLP u16
    int* gsg = (int*)(slg + (size_t)BGRAPHS * SLP);          // BGRAPHS*NPG
    int* gcg = gsg + (size_t)BGRAPHS * NPG;                  // BGRAPHS*NPG

    csr_build_kernel<<<BGRAPHS, 512, 0, stream>>>(src, dst, slg, gsg, gcg, nmask, dinv, sc, hp);

    // conv1 (64->32): gemm, then agg with fused bias+relu+score
    gemm_kernel<64, 32, 0><<<NNODES / 64, 256, 0, stream>>>(x, W1, nullptr, nullptr, hb, nullptr, nullptr, nullptr);
    gcn_agg_kernel<32, 1, 2, true, true><<<BGRAPHS * 2, 512, 0, stream>>>(hb, x0, dinv, sc, b1, p1, scoreb, slg, gsg, gcg);
    topk_kernel<32><<<BGRAPHS, 512, 0, stream>>>(scoreb, nmask, dinv, sc, p1, 360, slg, gsg, gcg);

    // conv2 (32->64): agg first (pool scale folded into sc), gemm w/ epilogue+score
    gcn_agg_kernel<32, 1, 2, false, false><<<BGRAPHS * 2, 512, 0, stream>>>(x0, hb, dinv, sc, nullptr, nullptr, nullptr, slg, gsg, gcg);
    gemm_kernel<32, 64, 2><<<NNODES / 64, 256, 0, stream>>>(hb, W2, b2, nmask, x1, p2, scoreb, nullptr);
    topk_kernel<64><<<BGRAPHS, 512, 0, stream>>>(scoreb, nmask, dinv, sc, p2, 324, slg, gsg, gcg);

    // conv3 (64->128): agg first, gemm w/ epilogue+score
    gcn_agg_kernel<64, 2, 2, false, false><<<BGRAPHS * 4, 512, 0, stream>>>(x1, hb, dinv, sc, nullptr, nullptr, nullptr, slg, gsg, gcg);
    gemm_kernel<64, 128, 2><<<NNODES / 64, 256, 0, stream>>>(hb, W3, b3, nmask, x0, p3, scoreb, nullptr);
    topk_kernel<128><<<BGRAPHS, 512, 0, stream>>>(scoreb, nmask, dinv, sc, p3, 292, slg, gsg, gcg);

    // conv4 (128->128): agg first, gemm with fused max-pool (no store)
    gcn_agg_kernel<128, 4, 1, false, false><<<BGRAPHS * 4, 512, 0, stream>>>(x0, hb, dinv, sc, nullptr, nullptr, nullptr, slg, gsg, gcg);
    gemm_kernel<128, 128, 3><<<NNODES / 64, 256, 0, stream>>>(hb, W4, b4, nmask, x1, nullptr, nullptr, hp);

    head_layer_kernel<128, 64><<<64, 128, 0, stream>>>(hp, Lw1, Lb1, g1, be1, a1);
    head_layer_kernel<64, 64><<<64, 128, 0, stream>>>(a1, Lw2, Lb2, g2, be2, a2);
    head_layer_kernel<64, 32><<<32, 128, 0, stream>>>(a2, Lw3, Lb3, g3, be3, a3);
    head_layer_kernel<32, 16><<<16, 128, 0, stream>>>(a3, Lw4, Lb4, g4, be4, a4);
    head_final_kernel<<<1, 128, 0, stream>>>(a4, Lw5, Lb5, (float*)d_out);
}